// Round 6
// baseline (579.625 us; speedup 1.0000x reference)
//
#include <hip/hip_runtime.h>
#include <stdint.h>
#include <math.h>

typedef __attribute__((ext_vector_type(8))) short short8;
typedef __attribute__((ext_vector_type(4))) float f32x4;
typedef __attribute__((ext_vector_type(16))) float f32x16;

#define CFENCE asm volatile("" ::: "memory")

__device__ __forceinline__ float b2f(unsigned short u) {
    union { unsigned int i; float f; } v; v.i = ((unsigned int)u) << 16; return v.f;
}
__device__ __forceinline__ unsigned short f2b(float f) {
    union { float f; unsigned int i; } v; v.f = f;
    unsigned int r = v.i + 0x7fffu + ((v.i >> 16) & 1u);
    return (unsigned short)(r >> 16);
}
__device__ __forceinline__ unsigned int cvt_pk_bf16(float lo, float hi) {
    unsigned int r;
    asm("v_cvt_pk_bf16_f32 %0, %1, %2" : "=v"(r) : "v"(lo), "v"(hi));
    return r;
}

__device__ __forceinline__ void gload_lds16(const void* g, void* l) {
    __builtin_amdgcn_global_load_lds((__attribute__((address_space(1))) void*)g,
                                     (__attribute__((address_space(3))) void*)l,
                                     16, 0, 0);
}

// ---------------------------------------------------------------------------
// qkv GEMM, 256x256 tile / BK=64 / 8 waves / phase-structured (T2+T3+T5).
// A (4096,1024) bf16, Bw (3072,1024) bf16 K-contig. Fused RoPE epilogue;
// Q cols pre-scaled by 0.125*log2e. LDS 128 KiB double-buffered, rows are
// 128B/8-chunk with source-side XOR swizzle (chunk j^(row&7)) so fragment
// ds_read_b128 is bank-conflict-free. One vmcnt(0) drain per K-tile.
// ---------------------------------------------------------------------------
__global__ __launch_bounds__(512)
void qkv_gemm256(const unsigned short* __restrict__ A,
                 const unsigned short* __restrict__ Bw,
                 const float* __restrict__ bias,
                 unsigned short* __restrict__ Cb,
                 const float* __restrict__ rope)
{
    __shared__ __align__(16) unsigned short As[2][16384];   // 256 rows x 64
    __shared__ __align__(16) unsigned short Bs[2][16384];
    const int tid = threadIdx.x, lane = tid & 63, wid = tid >> 6;
    const int wr = wid >> 2, wc = wid & 3;        // 2 x 4 wave grid
    const long brow = (long)blockIdx.y * 256;
    const long bcol = (long)blockIdx.x * 256;

    // staging: thread covers 2 rows (l=0,1) of a 128-row half; 16B chunks
    const int srow = tid >> 3;                    // 0..63
    const int sch = tid & 7;
    const unsigned short* gA = A + (brow + srow) * 1024 + ((sch ^ (srow & 7)) * 8);
    const unsigned short* gB = Bw + (bcol + srow) * 1024 + ((sch ^ (srow & 7)) * 8);

    f32x4 acc[8][4] = {};

    auto STAGE_A = [&](int c, int kt, int h) {
#pragma unroll
        for (int l = 0; l < 2; l++)
            gload_lds16(gA + (long)(h * 128 + l * 64) * 1024 + kt * 64,
                        &As[c][h * 8192 + l * 4096 + tid * 8]);
    };
    auto STAGE_B = [&](int c, int kt, int h) {
#pragma unroll
        for (int l = 0; l < 2; l++)
            gload_lds16(gB + (long)(h * 128 + l * 64) * 1024 + kt * 64,
                        &Bs[c][h * 8192 + l * 4096 + tid * 8]);
    };

    // prologue: tile 0 fully staged, drain, gate
    STAGE_A(0, 0, 0); STAGE_A(0, 0, 1); STAGE_B(0, 0, 0); STAGE_B(0, 0, 1);
    asm volatile("s_waitcnt vmcnt(0)" ::: "memory");
    __builtin_amdgcn_s_barrier();
    CFENCE;

    const int fr = lane & 15, g = lane >> 4;
    const int fsw = fr & 7;

    for (int t = 0; t < 16; ++t) {
        const int c = t & 1;
        const unsigned short* Ab = &As[c][0];
        const unsigned short* Bb = &Bs[c][0];
#pragma unroll
        for (int p = 0; p < 4; p++) {
            const int mh = p >> 1, nh = p & 1;
            // fragment ds-reads for this quadrant
            short8 af[4][2], bf[2][2];
#pragma unroll
            for (int mm = 0; mm < 4; mm++) {
                int r = wr * 128 + mh * 64 + mm * 16 + fr;
#pragma unroll
                for (int kk = 0; kk < 2; kk++)
                    af[mm][kk] = *(const short8*)(Ab + r * 64 + (((kk * 4 + g) ^ fsw) * 8));
            }
#pragma unroll
            for (int nn = 0; nn < 2; nn++) {
                int r = wc * 64 + nh * 32 + nn * 16 + fr;
#pragma unroll
                for (int kk = 0; kk < 2; kk++)
                    bf[nn][kk] = *(const short8*)(Bb + r * 64 + (((kk * 4 + g) ^ fsw) * 8));
            }
            // prefetch one half-tile of tile t+1 (A0,A1,B0,B1 across phases)
            if (t < 15) {
                if (p == 0) STAGE_A(c ^ 1, t + 1, 0);
                else if (p == 1) STAGE_A(c ^ 1, t + 1, 1);
                else if (p == 2) STAGE_B(c ^ 1, t + 1, 0);
                else STAGE_B(c ^ 1, t + 1, 1);
            }
            CFENCE;
            __builtin_amdgcn_s_barrier();   // mid barrier: cluster waves
            CFENCE;
            __builtin_amdgcn_s_setprio(1);
#pragma unroll
            for (int mm = 0; mm < 4; mm++)
#pragma unroll
                for (int nn = 0; nn < 2; nn++) {
                    int m = mh * 4 + mm, n = nh * 2 + nn;
                    acc[m][n] = __builtin_amdgcn_mfma_f32_16x16x32_bf16(af[mm][0], bf[nn][0], acc[m][n], 0, 0, 0);
                    acc[m][n] = __builtin_amdgcn_mfma_f32_16x16x32_bf16(af[mm][1], bf[nn][1], acc[m][n], 0, 0, 0);
                }
            __builtin_amdgcn_s_setprio(0);
            CFENCE;
            if (p == 3) asm volatile("s_waitcnt vmcnt(0)" ::: "memory");  // tile gate
            __builtin_amdgcn_s_barrier();   // end barrier
            CFENCE;
        }
    }

    // epilogue: bias + RoPE + Q-scale, bf16 store
    const int fq = (lane >> 4) * 4;
#pragma unroll
    for (int m = 0; m < 8; m++) {
#pragma unroll
        for (int n = 0; n < 4; n++) {
#pragma unroll
            for (int j = 0; j < 4; j++) {
                long row = brow + wr * 128 + m * 16 + fq + j;
                int col = (int)bcol + wc * 64 + n * 16 + fr;
                float v = acc[m][n][j] + bias[col];
                float part = __shfl_xor(v, 1);   // partner col (d^1), same row
                if (col < 2048) {
                    int d = col & 63;
                    int i2 = d >> 1;
                    int ntok = (int)(row & 1023);
                    float cc = rope[ntok * 32 + i2];
                    float ss = rope[32768 + ntok * 32 + i2];
                    v = (d & 1) ? (part * ss + v * cc) : (v * cc - part * ss);
                }
                if (col < 1024) v *= 0.18033688011112042f;   // 0.125*log2(e)
                Cb[row * 3072 + col] = f2b(v);
            }
        }
    }
}

// ---------------------------------------------------------------------------
// Tap-accumulation conv-as-GEMM (unchanged).
// ---------------------------------------------------------------------------
template<int KW, int CI>
__global__ __launch_bounds__(256)
void conv_gemm(const unsigned short* __restrict__ A, long sAb,
               const unsigned short* __restrict__ Bw, int CO,
               const float* __restrict__ bias,
               unsigned short* __restrict__ C, long sCb, int ldc, int crow_off)
{
    __shared__ __align__(16) unsigned short As[2][144 * 32];
    __shared__ __align__(16) unsigned short Bs[2][KW * 64 * 32];
    const int tid = threadIdx.x, lane = tid & 63, wid = tid >> 6;
    const int wr = wid >> 1, wc = wid & 1;
    const int z = blockIdx.z;
    const long brow = (long)blockIdx.y * 128;
    const long bcol = (long)blockIdx.x * 64;
    const unsigned short* Ab = A + z * sAb + brow * CI;
    const int srow = tid >> 2, scol = (tid & 3) * 8;

    f32x4 acc[4][2] = {};

    auto STAGE = [&](int buf, int kk) {
#pragma unroll
        for (int o = 0; o < 2; o++)
            gload_lds16(Ab + (long)(o * 64 + srow) * CI + kk + scol,
                        As[buf] + (o * 64 + wid * 16) * 32);
        if (wid == 0)
            gload_lds16(Ab + (long)(128 + srow) * CI + kk + scol,
                        As[buf] + 128 * 32);
#pragma unroll
        for (int dk = 0; dk < KW; dk++)
            gload_lds16(Bw + ((long)dk * CO + bcol + srow) * CI + kk + scol,
                        Bs[buf] + (dk * 64 + wid * 16) * 32);
    };

    STAGE(0, 0);
    const int fr = lane & 15, fk = (lane >> 4) * 8;
    int cur = 0;
    for (int kk = 0; kk < CI; kk += 32) {
        __syncthreads();
        if (kk + 32 < CI) STAGE(cur ^ 1, kk + 32);
        short8 bfr[KW][2];
#pragma unroll
        for (int dk = 0; dk < KW; dk++)
#pragma unroll
            for (int n = 0; n < 2; n++)
                bfr[dk][n] = *(const short8*)(Bs[cur] + (dk * 64 + wc * 32 + n * 16 + fr) * 32 + fk);
#pragma unroll
        for (int m = 0; m < 4; m++) {
#pragma unroll
            for (int dk = 0; dk < KW; dk++) {
                short8 af = *(const short8*)(As[cur] + (wr * 64 + m * 16 + fr + dk) * 32 + fk);
#pragma unroll
                for (int n = 0; n < 2; n++)
                    acc[m][n] = __builtin_amdgcn_mfma_f32_16x16x32_bf16(af, bfr[dk][n], acc[m][n], 0, 0, 0);
            }
        }
        cur ^= 1;
    }

    const int fq = (lane >> 4) * 4;
#pragma unroll
    for (int m = 0; m < 4; m++) {
#pragma unroll
        for (int n = 0; n < 2; n++) {
#pragma unroll
            for (int j = 0; j < 4; j++) {
                long row = brow + wr * 64 + m * 16 + fq + j;
                int col = (int)bcol + wc * 32 + n * 16 + fr;
                float v = acc[m][n][j] + bias[col];
                v = v / (1.f + __expf(-v));    // silu
                C[z * sCb + (crow_off + row) * ldc + col] = f2b(v);
            }
        }
    }
}

// ---------------------------------------------------------------------------
// Fused out-proj + gate GEMMs + residual epilogue (unchanged).
// ---------------------------------------------------------------------------
template<int LAST>
__global__ __launch_bounds__(256)
void fused_og(const unsigned short* __restrict__ A1, const unsigned short* __restrict__ B1,
              const float* __restrict__ b1,
              const unsigned short* __restrict__ A2, const unsigned short* __restrict__ B2,
              const float* __restrict__ b2,
              float* __restrict__ X, float* __restrict__ OUT)
{
    __shared__ __align__(16) unsigned short S[2][4][128 * 32];
    const int tid = threadIdx.x, lane = tid & 63, wid = tid >> 6;
    const int wr = wid >> 1, wc = wid & 1;
    const long brow = (long)blockIdx.y * 128;
    const long bcol = (long)blockIdx.x * 128;
    const int srow = tid >> 2, scol = (tid & 3) * 8;

    const unsigned short* g0 = A1 + (brow + srow) * 1024 + scol;
    const unsigned short* g1 = B1 + (bcol + srow) * 1024 + scol;
    const unsigned short* g2 = A2 + (brow + srow) * 1024 + scol;
    const unsigned short* g3 = B2 + (bcol + srow) * 1024 + scol;

    f32x4 acc1[4][4] = {}, acc2[4][4] = {};

    auto STAGE = [&](int buf, int kk) {
#pragma unroll
        for (int o = 0; o < 2; o++) {
            gload_lds16(g0 + (long)o * 65536 + kk, S[buf][0] + (o * 64 + wid * 16) * 32);
            gload_lds16(g1 + (long)o * 65536 + kk, S[buf][1] + (o * 64 + wid * 16) * 32);
            gload_lds16(g2 + (long)o * 65536 + kk, S[buf][2] + (o * 64 + wid * 16) * 32);
            gload_lds16(g3 + (long)o * 65536 + kk, S[buf][3] + (o * 64 + wid * 16) * 32);
        }
    };

    STAGE(0, 0);
    const int fr = lane & 15, fk = (lane >> 4) * 8;
    int cur = 0;
    for (int kk = 0; kk < 1024; kk += 32) {
        __syncthreads();
        if (kk + 32 < 1024) STAGE(cur ^ 1, kk + 32);
        {
            short8 af[4], bf[4];
#pragma unroll
            for (int m = 0; m < 4; m++)
                af[m] = *(const short8*)(S[cur][0] + (wr * 64 + m * 16 + fr) * 32 + fk);
#pragma unroll
            for (int n = 0; n < 4; n++)
                bf[n] = *(const short8*)(S[cur][1] + (wc * 64 + n * 16 + fr) * 32 + fk);
#pragma unroll
            for (int m = 0; m < 4; m++)
#pragma unroll
                for (int n = 0; n < 4; n++)
                    acc1[m][n] = __builtin_amdgcn_mfma_f32_16x16x32_bf16(af[m], bf[n], acc1[m][n], 0, 0, 0);
        }
        {
            short8 af[4], bf[4];
#pragma unroll
            for (int m = 0; m < 4; m++)
                af[m] = *(const short8*)(S[cur][2] + (wr * 64 + m * 16 + fr) * 32 + fk);
#pragma unroll
            for (int n = 0; n < 4; n++)
                bf[n] = *(const short8*)(S[cur][3] + (wc * 64 + n * 16 + fr) * 32 + fk);
#pragma unroll
            for (int m = 0; m < 4; m++)
#pragma unroll
                for (int n = 0; n < 4; n++)
                    acc2[m][n] = __builtin_amdgcn_mfma_f32_16x16x32_bf16(af[m], bf[n], acc2[m][n], 0, 0, 0);
        }
        cur ^= 1;
    }

    const int fq = (lane >> 4) * 4;
#pragma unroll
    for (int m = 0; m < 4; m++) {
#pragma unroll
        for (int n = 0; n < 4; n++) {
#pragma unroll
            for (int j = 0; j < 4; j++) {
                long row = brow + wr * 64 + m * 16 + fq + j;
                int col = (int)bcol + wc * 64 + n * 16 + fr;
                float v1 = acc1[m][n][j] + b1[col];
                float v2 = acc2[m][n][j] + b2[col];
                long idx = row * 1024 + col;
                float r = X[idx] + v1 / (1.f + __expf(-v2));
                if (LAST) OUT[idx] = r; else X[idx] = r;
            }
        }
    }
}

// ---------------------------------------------------------------------------
// V transpose with key-order permutation (unchanged).
// ---------------------------------------------------------------------------
__global__ __launch_bounds__(256)
void vtrans_kernel(const unsigned short* __restrict__ qkv, unsigned short* __restrict__ vt)
{
    __shared__ unsigned short sm[64][72];
    const int nt = blockIdx.x, bh = blockIdx.y;
    const int b = bh >> 4, h = bh & 15;
    const int tid = threadIdx.x;
    const unsigned short* vsrc = qkv + ((long)b * 1024 + nt * 64) * 3072 + 2048 + h * 64;
    const int r = tid >> 2, c0 = (tid & 3) * 16;
#pragma unroll
    for (int t = 0; t < 2; t++) {
        short8 v = *(const short8*)(vsrc + (long)r * 3072 + c0 + t * 8);
        *(short8*)(&sm[r][c0 + t * 8]) = v;
    }
    __syncthreads();
    const int d = tid >> 2, n0 = (tid & 3) * 16;
    unsigned short tmp[16];
#pragma unroll
    for (int i = 0; i < 16; i++) {
        int pi = (i & 3) | ((i & 4) << 1) | ((i & 8) >> 1);   // swap bits 2,3
        tmp[i] = sm[n0 + pi][d];
    }
    unsigned short* dst = vt + ((long)bh * 64 + d) * 1024 + nt * 64 + n0;
    *(short8*)(dst) = *(const short8*)(tmp);
    *(short8*)(dst + 8) = *(const short8*)(tmp + 8);
}

// ---------------------------------------------------------------------------
// Flash attention v4 (unchanged from round 4).
// ---------------------------------------------------------------------------
__global__ __launch_bounds__(256)
void attn_kernel(const unsigned short* __restrict__ qkv,
                 const unsigned short* __restrict__ vt,   // VTP (key-permuted)
                 const float* __restrict__ plog,
                 unsigned short* __restrict__ y)
{
    __shared__ __align__(16) unsigned short Kb[2][32 * 64];
    __shared__ __align__(16) unsigned short Vb[2][64 * 32];
    __shared__ float pl[1024];

    const int bh = blockIdx.x;
    const int qt = blockIdx.y;
    const int b = bh >> 4, h = bh & 15;
    const int tid = threadIdx.x, lane = tid & 63, wid = tid >> 6;
    const int c = lane & 31;
    const int hh = lane >> 5;

    const long nb = (long)b * 1024;
    const unsigned short* qbase = qkv + nb * 3072 + h * 64;
    const unsigned short* kbase = qbase + 1024;
    const unsigned short* vtb = vt + (long)bh * 65536;

    for (int i = tid; i < 1024; i += 256) pl[i] = plog[b * 1024 + i] * 1.4426950408889634f;

    const int krow = (tid >> 3) & 31;
    const int kchk = (lane & 7) ^ ((lane >> 3) & 7);
    const unsigned short* gk = kbase + (long)krow * 3072 + kchk * 8;
    unsigned short* lk = Kb[0] + wid * 512;

    const int vrow = tid >> 2;
    const int vchk = (tid & 3) ^ ((tid >> 2) & 3);
    const unsigned short* gv = vtb + (long)vrow * 1024 + vchk * 8;
    unsigned short* lv = Vb[0] + wid * 512;

    auto STAGE = [&](int buf, int kt) {
        gload_lds16(gk + (long)kt * 3072, lk + buf * 2048);
        gload_lds16(gv + kt, lv + buf * 2048);
    };

    const int q0 = qt * 128 + wid * 32;
    short8 qf[4];
#pragma unroll
    for (int d = 0; d < 4; d++)
        qf[d] = *(const short8*)(qbase + (long)(q0 + c) * 3072 + d * 16 + hh * 8);

    float m_run = -1e30f, l_run = 0.f;
    f32x16 o0 = {}, o1 = {};

    STAGE(0, 0);
    int cur = 0;
    for (int kt = 0; kt < 1024; kt += 32) {
        __syncthreads();
        if (kt + 32 < 1024) STAGE(cur ^ 1, kt + 32);

        short8 kf[4];
#pragma unroll
        for (int d = 0; d < 4; d++)
            kf[d] = *(const short8*)(Kb[cur] + c * 64 + (((2 * d + hh) ^ (c & 7)) * 8));

        f32x16 s = {};
#pragma unroll
        for (int d = 0; d < 4; d++)
            s = __builtin_amdgcn_mfma_f32_32x32x16_bf16(kf[d], qf[d], s, 0, 0, 0);

        float mx = -1e30f;
#pragma unroll
        for (int r = 0; r < 16; r++) {
            int key = (r & 3) + 8 * (r >> 2) + 4 * hh;
            float pv = s[r] + pl[kt + key];
            s[r] = pv;
            mx = fmaxf(mx, pv);
        }
        mx = fmaxf(mx, __shfl_xor(mx, 32));

        if (!__all(mx - m_run <= 11.5f)) {     // defer-max (T13, log2 domain)
            float mnew = fmaxf(m_run, mx);
            float f = __builtin_amdgcn_exp2f(m_run - mnew);
            l_run *= f;
#pragma unroll
            for (int r = 0; r < 16; r++) { o0[r] *= f; o1[r] *= f; }
            m_run = mnew;
        }

        float sum = 0.f;
#pragma unroll
        for (int r = 0; r < 16; r++) {
            s[r] = __builtin_amdgcn_exp2f(s[r] - m_run);
            sum += s[r];
        }
        sum += __shfl_xor(sum, 32);
        l_run += sum;

        union U8 { unsigned int u[4]; short8 v; } B1, B2;
#pragma unroll
        for (int t = 0; t < 4; t++) {
            B1.u[t] = cvt_pk_bf16(s[2 * t], s[2 * t + 1]);
            B2.u[t] = cvt_pk_bf16(s[8 + 2 * t], s[9 + 2 * t]);
        }

        const int vsw = c & 3;
        short8 va00 = *(const short8*)(Vb[cur] + c * 32 + ((hh ^ vsw) * 8));
        short8 va01 = *(const short8*)(Vb[cur] + c * 32 + (((2 + hh) ^ vsw) * 8));
        short8 va10 = *(const short8*)(Vb[cur] + (c + 32) * 32 + ((hh ^ vsw) * 8));
        short8 va11 = *(const short8*)(Vb[cur] + (c + 32) * 32 + (((2 + hh) ^ vsw) * 8));

        o0 = __builtin_amdgcn_mfma_f32_32x32x16_bf16(va00, B1.v, o0, 0, 0, 0);
        o0 = __builtin_amdgcn_mfma_f32_32x32x16_bf16(va01, B2.v, o0, 0, 0, 0);
        o1 = __builtin_amdgcn_mfma_f32_32x32x16_bf16(va10, B1.v, o1, 0, 0, 0);
        o1 = __builtin_amdgcn_mfma_f32_32x32x16_bf16(va11, B2.v, o1, 0, 0, 0);

        cur ^= 1;
    }

    float inv = 1.f / l_run;
    unsigned short* yr = y + (nb + q0 + c) * 1024 + h * 64;
#pragma unroll
    for (int a = 0; a < 4; a++) {
        int d0 = 8 * a + 4 * hh;
        *(unsigned int*)(yr + d0)      = cvt_pk_bf16(o0[4 * a] * inv, o0[4 * a + 1] * inv);
        *(unsigned int*)(yr + d0 + 2)  = cvt_pk_bf16(o0[4 * a + 2] * inv, o0[4 * a + 3] * inv);
        *(unsigned int*)(yr + 32 + d0)     = cvt_pk_bf16(o1[4 * a] * inv, o1[4 * a + 1] * inv);
        *(unsigned int*)(yr + 32 + d0 + 2) = cvt_pk_bf16(o1[4 * a + 2] * inv, o1[4 * a + 3] * inv);
    }
}

// --------------------------------------------------------------------------
__global__ __launch_bounds__(256)
void zcrms_kernel(const float* __restrict__ x, const float* __restrict__ g,
                  unsigned short* __restrict__ hn)
{
    __shared__ float red[8];
    const long row = blockIdx.x;
    const int tid = threadIdx.x;
    const float* xr = x + row * 1024;
    float4 v = *(const float4*)(xr + tid * 4);
    float s = v.x + v.y + v.z + v.w;
#pragma unroll
    for (int m = 32; m; m >>= 1) s += __shfl_xor(s, m);
    const int lane = tid & 63, wid = tid >> 6;
    if (lane == 0) red[wid] = s;
    __syncthreads();
    float mean = (red[0] + red[1] + red[2] + red[3]) * (1.f / 1024.f);
    float c0 = v.x - mean, c1 = v.y - mean, c2 = v.z - mean, c3 = v.w - mean;
    float s2 = c0 * c0 + c1 * c1 + c2 * c2 + c3 * c3;
#pragma unroll
    for (int m = 32; m; m >>= 1) s2 += __shfl_xor(s2, m);
    if (lane == 0) red[4 + wid] = s2;
    __syncthreads();
    float rinv = rsqrtf((red[4] + red[5] + red[6] + red[7]) * (1.f / 1024.f) + 1e-8f);
    const float* gr = g + tid * 4;
    unsigned int lo = (unsigned int)f2b(c0 * rinv * gr[0]) | ((unsigned int)f2b(c1 * rinv * gr[1]) << 16);
    unsigned int hi = (unsigned int)f2b(c2 * rinv * gr[2]) | ((unsigned int)f2b(c3 * rinv * gr[3]) << 16);
    uint2 u; u.x = lo; u.y = hi;
    *(uint2*)(hn + row * 1024 + tid * 4) = u;
}

__global__ __launch_bounds__(1024)
void embed_kernel(const float* __restrict__ patches, const float* __restrict__ W,
                  const float* __restrict__ bias, float* __restrict__ x,
                  unsigned short* __restrict__ xpad)
{
    __shared__ float sp[8][75];
    const long r0 = (long)blockIdx.x * 8;
    const int tid = threadIdx.x;
    for (int i = tid; i < 600; i += 1024) sp[i / 75][i % 75] = patches[r0 * 75 + i];
    __syncthreads();
    float acc[8];
    float bb = bias[tid];
#pragma unroll
    for (int j = 0; j < 8; j++) acc[j] = bb;
    for (int p = 0; p < 75; p++) {
        float w = W[p * 1024 + tid];
#pragma unroll
        for (int j = 0; j < 8; j++) acc[j] += sp[j][p] * w;
    }
#pragma unroll
    for (int j = 0; j < 8; j++) {
        long r = r0 + j;
        x[r * 1024 + tid] = acc[j];
        long bb2 = r >> 10, n = r & 1023;
        xpad[(bb2 * 1028 + n + 2) * 1024 + tid] = f2b(acc[j]);
    }
}

__global__ void rope_table_kernel(float* __restrict__ tab)
{
    int idx = blockIdx.x * 256 + threadIdx.x;   // 32768
    int n = idx >> 5, i = idx & 31;
    float inv = powf(10000.0f, -(float)i * (1.0f / 32.0f));
    float ang = (float)n * inv;
    tab[idx] = cosf(ang);
    tab[32768 + idx] = sinf(ang);
}

__global__ __launch_bounds__(256)
void conv3_kernel(const unsigned short* __restrict__ h2, const float* __restrict__ w3,
                  const float* __restrict__ b3, float* __restrict__ logits)
{
    const long row = (long)blockIdx.x * 4 + (threadIdx.x >> 6);
    const int lane = threadIdx.x & 63;
    const unsigned short* hr = h2 + row * 256;
    float s = 0.f;
#pragma unroll
    for (int t = 0; t < 4; t++) s += b2f(hr[lane + t * 64]) * w3[lane + t * 64];
#pragma unroll
    for (int m = 32; m; m >>= 1) s += __shfl_xor(s, m);
    if (lane == 0) logits[row] = s + b3[0];
}

__global__ __launch_bounds__(256)
void winmax_kernel(const float* __restrict__ logits, float* __restrict__ win)
{
    __shared__ float red[4];
    const int b = blockIdx.x, tid = threadIdx.x;
    float m = -1e30f;
    for (int i = tid; i < 1024; i += 256) m = fmaxf(m, logits[b * 1024 + i]);
#pragma unroll
    for (int k = 32; k; k >>= 1) m = fmaxf(m, __shfl_xor(m, k));
    if ((tid & 63) == 0) red[tid >> 6] = m;
    __syncthreads();
    if (tid == 0) win[b] = fmaxf(fmaxf(red[0], red[1]), fmaxf(red[2], red[3]));
}

// f32 (K,Nc) -> bf16 (Nc,K), batched over z
__global__ __launch_bounds__(256)
void wtrans_kernel(const float* __restrict__ in, unsigned short* __restrict__ out,
                   int K, int Nc)
{
    __shared__ float tile[32][33];
    const long base = (long)blockIdx.z * K * Nc;
    const int k0 = blockIdx.y * 32, n0 = blockIdx.x * 32;
    const int tx = threadIdx.x & 31, ty = threadIdx.x >> 5;
#pragma unroll
    for (int r = ty; r < 32; r += 8) tile[r][tx] = in[base + (long)(k0 + r) * Nc + n0 + tx];
    __syncthreads();
#pragma unroll
    for (int r = ty; r < 32; r += 8) out[base + (long)(n0 + r) * K + k0 + tx] = f2b(tile[tx][r]);
}

// (Co,Ci,Kw) f32 -> [dk][co][ci] bf16
__global__ void wconv_tap_kernel(const float* __restrict__ in, unsigned short* __restrict__ out,
                                 int CI, int KW, int CO, long total)
{
    long idx = (long)blockIdx.x * 256 + threadIdx.x;
    if (idx >= total) return;
    int ci = (int)(idx % CI);
    long t = idx / CI;
    int co = (int)(t % CO);
    int dk = (int)(t / CO);
    out[idx] = f2b(in[((long)co * CI + ci) * KW + dk]);
}

// ---------------------------------------------------------------------------
extern "C" void kernel_launch(void* const* d_in, const int* in_sizes, int n_in,
                              void* d_out, int out_size, void* d_ws, size_t ws_size,
                              hipStream_t stream)
{
    (void)in_sizes; (void)n_in; (void)out_size; (void)ws_size;
    const float* patches = (const float*)d_in[0];
    const float* embed_w = (const float*)d_in[1];
    const float* embed_b = (const float*)d_in[2];
    const float* bd_w1 = (const float*)d_in[3];
    const float* bd_b1 = (const float*)d_in[4];
    const float* bd_w2 = (const float*)d_in[5];
    const float* bd_b2 = (const float*)d_in[6];
    const float* bd_w3 = (const float*)d_in[7];
    const float* bd_b3 = (const float*)d_in[8];
    const float* norm_g = (const float*)d_in[9];
    const float* qkv_w = (const float*)d_in[10];
    const float* qkv_b = (const float*)d_in[11];
    const float* out_w = (const float*)d_in[12];
    const float* out_b = (const float*)d_in[13];
    const float* gate_w = (const float*)d_in[14];
    const float* gate_b = (const float*)d_in[15];

    char* p = (char*)d_ws;
    auto alloc = [&](size_t bytes) { char* r = p; p += (bytes + 255) & ~(size_t)255; return r; };
    unsigned short* WQ   = (unsigned short*)alloc(3ll * 3072 * 1024 * 2);
    unsigned short* WO   = (unsigned short*)alloc(3ll * 1024 * 1024 * 2);
    unsigned short* WG   = (unsigned short*)alloc(3ll * 1024 * 1024 * 2);
    unsigned short* W1S  = (unsigned short*)alloc(5ll * 512 * 1024 * 2);
    unsigned short* W2S  = (unsigned short*)alloc(3ll * 256 * 512 * 2);
    unsigned short* XPAD = (unsigned short*)alloc(4ll * 1028 * 1024 * 2);
    unsigned short* H1P  = (unsigned short*)alloc(4ll * 1026 * 512 * 2);
    unsigned short* H2   = (unsigned short*)alloc(4ll * 1024 * 256 * 2);
    float*          X    = (float*)alloc(4ll * 1024 * 1024 * 4);
    unsigned short* HN   = (unsigned short*)alloc(4096ll * 1024 * 2);
    unsigned short* QKV  = (unsigned short*)alloc(4096ll * 3072 * 2);
    unsigned short* YATT = (unsigned short*)alloc(4096ll * 1024 * 2);
    float*          LOGI = (float*)alloc(4096 * 4);
    float*          ROPE = (float*)alloc(65536 * 4);
    // VTP (B,H,64,1024) bf16 = 8MB aliased onto XPAD (conv pipeline done first)
    unsigned short* VT   = XPAD;

    hipMemsetAsync(XPAD, 0, 4ll * 1028 * 1024 * 2, stream);
    hipMemsetAsync(H1P, 0, 4ll * 1026 * 512 * 2, stream);

    wtrans_kernel<<<dim3(96, 32, 3), 256, 0, stream>>>(qkv_w, WQ, 1024, 3072);
    wtrans_kernel<<<dim3(32, 32, 3), 256, 0, stream>>>(out_w, WO, 1024, 1024);
    wtrans_kernel<<<dim3(32, 32, 3), 256, 0, stream>>>(gate_w, WG, 1024, 1024);
    wconv_tap_kernel<<<10240, 256, 0, stream>>>(bd_w1, W1S, 1024, 5, 512, 5ll * 512 * 1024);
    wconv_tap_kernel<<<1536, 256, 0, stream>>>(bd_w2, W2S, 512, 3, 256, 3ll * 256 * 512);
    rope_table_kernel<<<128, 256, 0, stream>>>(ROPE);
    embed_kernel<<<512, 1024, 0, stream>>>(patches, embed_w, embed_b, X, XPAD);

    conv_gemm<5, 1024><<<dim3(8, 8, 4), 256, 0, stream>>>(XPAD, 1028ll * 1024, W1S, 512, bd_b1,
                                                          H1P, 1026ll * 512, 512, 1);
    conv_gemm<3, 512><<<dim3(4, 8, 4), 256, 0, stream>>>(H1P, 1026ll * 512, W2S, 256, bd_b2,
                                                         H2, 1024ll * 256, 256, 0);
    conv3_kernel<<<1024, 256, 0, stream>>>(H2, bd_w3, bd_b3, LOGI);
    winmax_kernel<<<4, 256, 0, stream>>>(LOGI, (float*)d_out + 4194304);

    for (int l = 0; l < 3; l++) {
        zcrms_kernel<<<4096, 256, 0, stream>>>(X, norm_g + l * 1024, HN);
        qkv_gemm256<<<dim3(12, 16), 512, 0, stream>>>(HN, WQ + (long)l * 3072 * 1024,
                                                      qkv_b + l * 3072, QKV, ROPE);
        vtrans_kernel<<<dim3(16, 64), 256, 0, stream>>>(QKV, VT);
        attn_kernel<<<dim3(64, 8), 256, 0, stream>>>(QKV, VT, LOGI, YATT);
        if (l < 2)
            fused_og<0><<<dim3(8, 32), 256, 0, stream>>>(YATT, WO + (long)l * 1024 * 1024, out_b + l * 1024,
                                                         HN, WG + (long)l * 1024 * 1024, gate_b + l * 1024,
                                                         X, nullptr);
        else
            fused_og<1><<<dim3(8, 32), 256, 0, stream>>>(YATT, WO + (long)l * 1024 * 1024, out_b + l * 1024,
                                                         HN, WG + (long)l * 1024 * 1024, gate_b + l * 1024,
                                                         X, (float*)d_out);
    }
}

// Round 7
// 522.117 us; speedup vs baseline: 1.1101x; 1.1101x over previous
//
#include <hip/hip_runtime.h>
#include <stdint.h>
#include <math.h>

typedef __attribute__((ext_vector_type(8))) short short8;
typedef __attribute__((ext_vector_type(4))) float f32x4;
typedef __attribute__((ext_vector_type(16))) float f32x16;

__device__ __forceinline__ float b2f(unsigned short u) {
    union { unsigned int i; float f; } v; v.i = ((unsigned int)u) << 16; return v.f;
}
__device__ __forceinline__ unsigned short f2b(float f) {
    union { float f; unsigned int i; } v; v.f = f;
    unsigned int r = v.i + 0x7fffu + ((v.i >> 16) & 1u);
    return (unsigned short)(r >> 16);
}
__device__ __forceinline__ unsigned int cvt_pk_bf16(float lo, float hi) {
    unsigned int r;
    asm("v_cvt_pk_bf16_f32 %0, %1, %2" : "=v"(r) : "v"(lo), "v"(hi));
    return r;
}

__device__ __forceinline__ void gload_lds16(const void* g, void* l) {
    __builtin_amdgcn_global_load_lds((__attribute__((address_space(1))) void*)g,
                                     (__attribute__((address_space(3))) void*)l,
                                     16, 0, 0);
}

// ---------------------------------------------------------------------------
// qkv GEMM (128x128, m97 structure — round-5 proven) with fused RoPE epilogue
// and fused V->VT transposed store.
//  - cols <2048 (Q,K): bias + RoPE (+0.125*log2e scale on Q), store to QKV.
//  - cols >=2048 (V): bias, store DIRECTLY into VT[b*1024 + (col-2048)][token]
//    with the key-permutation pi (swap bits 2,3 of token%16 == fq 4<->8 remap);
//    QKV's V region is never written. Replaces the vtrans kernel.
// ---------------------------------------------------------------------------
__global__ __launch_bounds__(256)
void qkv_gemm(const unsigned short* __restrict__ A,
              const unsigned short* __restrict__ Bw,
              const float* __restrict__ bias,
              unsigned short* __restrict__ Cb,
              unsigned short* __restrict__ vt,
              const float* __restrict__ rope)
{
    __shared__ __align__(16) unsigned short As[128 * 32];
    __shared__ __align__(16) unsigned short Bs[128 * 32];
    const int tid = threadIdx.x;
    const int lane = tid & 63, wid = tid >> 6;
    const int wr = wid >> 1, wc = wid & 1;
    const long brow = (long)blockIdx.y * 128;
    const long bcol = (long)blockIdx.x * 128;

    const int arow = tid >> 2;
    const int acol = (tid & 3) * 8;
    const unsigned short* ga0 = A + (brow + arow) * 1024 + acol;
    const unsigned short* ga1 = A + (brow + 64 + arow) * 1024 + acol;
    const unsigned short* gb0 = Bw + (bcol + arow) * 1024 + acol;
    const unsigned short* gb1 = Bw + (bcol + 64 + arow) * 1024 + acol;
    unsigned short* la0 = As + wid * 512;
    unsigned short* la1 = As + 2048 + wid * 512;
    unsigned short* lb0 = Bs + wid * 512;
    unsigned short* lb1 = Bs + 2048 + wid * 512;

    f32x4 acc[4][4] = {};

    for (int kk = 0; kk < 1024; kk += 32) {
        gload_lds16(ga0 + kk, la0);
        gload_lds16(ga1 + kk, la1);
        gload_lds16(gb0 + kk, lb0);
        gload_lds16(gb1 + kk, lb1);
        __syncthreads();
        const int fr = lane & 15, fk = (lane >> 4) * 8;
        short8 af[4], bfrag[4];
#pragma unroll
        for (int m = 0; m < 4; m++)
            af[m] = *(const short8*)(As + (wr * 64 + m * 16 + fr) * 32 + fk);
#pragma unroll
        for (int n = 0; n < 4; n++)
            bfrag[n] = *(const short8*)(Bs + (wc * 64 + n * 16 + fr) * 32 + fk);
#pragma unroll
        for (int m = 0; m < 4; m++)
#pragma unroll
            for (int n = 0; n < 4; n++)
                acc[m][n] = __builtin_amdgcn_mfma_f32_16x16x32_bf16(af[m], bfrag[n], acc[m][n], 0, 0, 0);
        __syncthreads();
    }

    const int fr = lane & 15;
    const int fq = (lane >> 4) * 4;
    if (bcol < 2048) {
        // Q/K blocks: bias + RoPE (+Q scale), bf16 store into QKV
#pragma unroll
        for (int m = 0; m < 4; m++) {
#pragma unroll
            for (int n = 0; n < 4; n++) {
#pragma unroll
                for (int j = 0; j < 4; j++) {
                    long row = brow + wr * 64 + m * 16 + fq + j;
                    int col = (int)bcol + wc * 64 + n * 16 + fr;
                    float v = acc[m][n][j] + bias[col];
                    float part = __shfl_xor(v, 1);   // partner col (d^1), same row
                    int d = col & 63;
                    int i2 = d >> 1;
                    int ntok = (int)(row & 1023);
                    float cc = rope[ntok * 32 + i2];
                    float ss = rope[32768 + ntok * 32 + i2];
                    v = (d & 1) ? (part * ss + v * cc) : (v * cc - part * ss);
                    if (col < 1024) v *= 0.18033688011112042f;   // 0.125*log2(e)
                    Cb[row * 3072 + col] = f2b(v);
                }
            }
        }
    } else {
        // V blocks: bias, store transposed+key-permuted into VT.
        // pi (swap bits 2,3 of token%16) == remap of the 4-row group fq: 4<->8.
        const int fqp = (fq == 4) ? 8 : (fq == 8) ? 4 : fq;
        const int b = (int)(brow >> 10);
        const int rb = (int)(brow & 1023);
        unsigned short* vtb = vt + ((long)b << 20);
#pragma unroll
        for (int m = 0; m < 4; m++) {
            int ntok = rb + wr * 64 + m * 16 + fqp;
#pragma unroll
            for (int n = 0; n < 4; n++) {
                int hd = (int)bcol - 2048 + wc * 64 + n * 16 + fr;   // h*64+d
                float bb = bias[2048 + hd];
                uint2 u;
                u.x = cvt_pk_bf16(acc[m][n][0] + bb, acc[m][n][1] + bb);
                u.y = cvt_pk_bf16(acc[m][n][2] + bb, acc[m][n][3] + bb);
                *(uint2*)(vtb + (long)hd * 1024 + ntok) = u;
            }
        }
    }
}

// ---------------------------------------------------------------------------
// Tap-accumulation conv-as-GEMM (unchanged).
// ---------------------------------------------------------------------------
template<int KW, int CI>
__global__ __launch_bounds__(256)
void conv_gemm(const unsigned short* __restrict__ A, long sAb,
               const unsigned short* __restrict__ Bw, int CO,
               const float* __restrict__ bias,
               unsigned short* __restrict__ C, long sCb, int ldc, int crow_off)
{
    __shared__ __align__(16) unsigned short As[2][144 * 32];
    __shared__ __align__(16) unsigned short Bs[2][KW * 64 * 32];
    const int tid = threadIdx.x, lane = tid & 63, wid = tid >> 6;
    const int wr = wid >> 1, wc = wid & 1;
    const int z = blockIdx.z;
    const long brow = (long)blockIdx.y * 128;
    const long bcol = (long)blockIdx.x * 64;
    const unsigned short* Ab = A + z * sAb + brow * CI;
    const int srow = tid >> 2, scol = (tid & 3) * 8;

    f32x4 acc[4][2] = {};

    auto STAGE = [&](int buf, int kk) {
#pragma unroll
        for (int o = 0; o < 2; o++)
            gload_lds16(Ab + (long)(o * 64 + srow) * CI + kk + scol,
                        As[buf] + (o * 64 + wid * 16) * 32);
        if (wid == 0)
            gload_lds16(Ab + (long)(128 + srow) * CI + kk + scol,
                        As[buf] + 128 * 32);
#pragma unroll
        for (int dk = 0; dk < KW; dk++)
            gload_lds16(Bw + ((long)dk * CO + bcol + srow) * CI + kk + scol,
                        Bs[buf] + (dk * 64 + wid * 16) * 32);
    };

    STAGE(0, 0);
    const int fr = lane & 15, fk = (lane >> 4) * 8;
    int cur = 0;
    for (int kk = 0; kk < CI; kk += 32) {
        __syncthreads();
        if (kk + 32 < CI) STAGE(cur ^ 1, kk + 32);
        short8 bfr[KW][2];
#pragma unroll
        for (int dk = 0; dk < KW; dk++)
#pragma unroll
            for (int n = 0; n < 2; n++)
                bfr[dk][n] = *(const short8*)(Bs[cur] + (dk * 64 + wc * 32 + n * 16 + fr) * 32 + fk);
#pragma unroll
        for (int m = 0; m < 4; m++) {
#pragma unroll
            for (int dk = 0; dk < KW; dk++) {
                short8 af = *(const short8*)(As[cur] + (wr * 64 + m * 16 + fr + dk) * 32 + fk);
#pragma unroll
                for (int n = 0; n < 2; n++)
                    acc[m][n] = __builtin_amdgcn_mfma_f32_16x16x32_bf16(af, bfr[dk][n], acc[m][n], 0, 0, 0);
            }
        }
        cur ^= 1;
    }

    const int fq = (lane >> 4) * 4;
#pragma unroll
    for (int m = 0; m < 4; m++) {
#pragma unroll
        for (int n = 0; n < 2; n++) {
#pragma unroll
            for (int j = 0; j < 4; j++) {
                long row = brow + wr * 64 + m * 16 + fq + j;
                int col = (int)bcol + wc * 32 + n * 16 + fr;
                float v = acc[m][n][j] + bias[col];
                v = v / (1.f + __expf(-v));    // silu
                C[z * sCb + (crow_off + row) * ldc + col] = f2b(v);
            }
        }
    }
}

// ---------------------------------------------------------------------------
// Fused out-proj + gate GEMMs + residual epilogue (unchanged).
// ---------------------------------------------------------------------------
template<int LAST>
__global__ __launch_bounds__(256)
void fused_og(const unsigned short* __restrict__ A1, const unsigned short* __restrict__ B1,
              const float* __restrict__ b1,
              const unsigned short* __restrict__ A2, const unsigned short* __restrict__ B2,
              const float* __restrict__ b2,
              float* __restrict__ X, float* __restrict__ OUT)
{
    __shared__ __align__(16) unsigned short S[2][4][128 * 32];
    const int tid = threadIdx.x, lane = tid & 63, wid = tid >> 6;
    const int wr = wid >> 1, wc = wid & 1;
    const long brow = (long)blockIdx.y * 128;
    const long bcol = (long)blockIdx.x * 128;
    const int srow = tid >> 2, scol = (tid & 3) * 8;

    const unsigned short* g0 = A1 + (brow + srow) * 1024 + scol;
    const unsigned short* g1 = B1 + (bcol + srow) * 1024 + scol;
    const unsigned short* g2 = A2 + (brow + srow) * 1024 + scol;
    const unsigned short* g3 = B2 + (bcol + srow) * 1024 + scol;

    f32x4 acc1[4][4] = {}, acc2[4][4] = {};

    auto STAGE = [&](int buf, int kk) {
#pragma unroll
        for (int o = 0; o < 2; o++) {
            gload_lds16(g0 + (long)o * 65536 + kk, S[buf][0] + (o * 64 + wid * 16) * 32);
            gload_lds16(g1 + (long)o * 65536 + kk, S[buf][1] + (o * 64 + wid * 16) * 32);
            gload_lds16(g2 + (long)o * 65536 + kk, S[buf][2] + (o * 64 + wid * 16) * 32);
            gload_lds16(g3 + (long)o * 65536 + kk, S[buf][3] + (o * 64 + wid * 16) * 32);
        }
    };

    STAGE(0, 0);
    const int fr = lane & 15, fk = (lane >> 4) * 8;
    int cur = 0;
    for (int kk = 0; kk < 1024; kk += 32) {
        __syncthreads();
        if (kk + 32 < 1024) STAGE(cur ^ 1, kk + 32);
        {
            short8 af[4], bf[4];
#pragma unroll
            for (int m = 0; m < 4; m++)
                af[m] = *(const short8*)(S[cur][0] + (wr * 64 + m * 16 + fr) * 32 + fk);
#pragma unroll
            for (int n = 0; n < 4; n++)
                bf[n] = *(const short8*)(S[cur][1] + (wc * 64 + n * 16 + fr) * 32 + fk);
#pragma unroll
            for (int m = 0; m < 4; m++)
#pragma unroll
                for (int n = 0; n < 4; n++)
                    acc1[m][n] = __builtin_amdgcn_mfma_f32_16x16x32_bf16(af[m], bf[n], acc1[m][n], 0, 0, 0);
        }
        {
            short8 af[4], bf[4];
#pragma unroll
            for (int m = 0; m < 4; m++)
                af[m] = *(const short8*)(S[cur][2] + (wr * 64 + m * 16 + fr) * 32 + fk);
#pragma unroll
            for (int n = 0; n < 4; n++)
                bf[n] = *(const short8*)(S[cur][3] + (wc * 64 + n * 16 + fr) * 32 + fk);
#pragma unroll
            for (int m = 0; m < 4; m++)
#pragma unroll
                for (int n = 0; n < 4; n++)
                    acc2[m][n] = __builtin_amdgcn_mfma_f32_16x16x32_bf16(af[m], bf[n], acc2[m][n], 0, 0, 0);
        }
        cur ^= 1;
    }

    const int fq = (lane >> 4) * 4;
#pragma unroll
    for (int m = 0; m < 4; m++) {
#pragma unroll
        for (int n = 0; n < 4; n++) {
#pragma unroll
            for (int j = 0; j < 4; j++) {
                long row = brow + wr * 64 + m * 16 + fq + j;
                int col = (int)bcol + wc * 64 + n * 16 + fr;
                float v1 = acc1[m][n][j] + b1[col];
                float v2 = acc2[m][n][j] + b2[col];
                long idx = row * 1024 + col;
                float r = X[idx] + v1 / (1.f + __expf(-v2));
                if (LAST) OUT[idx] = r; else X[idx] = r;
            }
        }
    }
}

// ---------------------------------------------------------------------------
// Flash attention v4 (unchanged from round 5): swapped-QK^T 32x32 +
// transposed PV; exp2-domain softmax; LDS-staged K/V, pre-swizzled source.
// ---------------------------------------------------------------------------
__global__ __launch_bounds__(256)
void attn_kernel(const unsigned short* __restrict__ qkv,
                 const unsigned short* __restrict__ vt,   // VTP (key-permuted)
                 const float* __restrict__ plog,
                 unsigned short* __restrict__ y)
{
    __shared__ __align__(16) unsigned short Kb[2][32 * 64];
    __shared__ __align__(16) unsigned short Vb[2][64 * 32];
    __shared__ float pl[1024];

    const int bh = blockIdx.x;
    const int qt = blockIdx.y;
    const int b = bh >> 4, h = bh & 15;
    const int tid = threadIdx.x, lane = tid & 63, wid = tid >> 6;
    const int c = lane & 31;
    const int hh = lane >> 5;

    const long nb = (long)b * 1024;
    const unsigned short* qbase = qkv + nb * 3072 + h * 64;
    const unsigned short* kbase = qbase + 1024;
    const unsigned short* vtb = vt + (long)bh * 65536;

    for (int i = tid; i < 1024; i += 256) pl[i] = plog[b * 1024 + i] * 1.4426950408889634f;

    const int krow = (tid >> 3) & 31;
    const int kchk = (lane & 7) ^ ((lane >> 3) & 7);
    const unsigned short* gk = kbase + (long)krow * 3072 + kchk * 8;
    unsigned short* lk = Kb[0] + wid * 512;

    const int vrow = tid >> 2;
    const int vchk = (tid & 3) ^ ((tid >> 2) & 3);
    const unsigned short* gv = vtb + (long)vrow * 1024 + vchk * 8;
    unsigned short* lv = Vb[0] + wid * 512;

    auto STAGE = [&](int buf, int kt) {
        gload_lds16(gk + (long)kt * 3072, lk + buf * 2048);
        gload_lds16(gv + kt, lv + buf * 2048);
    };

    const int q0 = qt * 128 + wid * 32;
    short8 qf[4];
#pragma unroll
    for (int d = 0; d < 4; d++)
        qf[d] = *(const short8*)(qbase + (long)(q0 + c) * 3072 + d * 16 + hh * 8);

    float m_run = -1e30f, l_run = 0.f;
    f32x16 o0 = {}, o1 = {};

    STAGE(0, 0);
    int cur = 0;
    for (int kt = 0; kt < 1024; kt += 32) {
        __syncthreads();
        if (kt + 32 < 1024) STAGE(cur ^ 1, kt + 32);

        short8 kf[4];
#pragma unroll
        for (int d = 0; d < 4; d++)
            kf[d] = *(const short8*)(Kb[cur] + c * 64 + (((2 * d + hh) ^ (c & 7)) * 8));

        f32x16 s = {};
#pragma unroll
        for (int d = 0; d < 4; d++)
            s = __builtin_amdgcn_mfma_f32_32x32x16_bf16(kf[d], qf[d], s, 0, 0, 0);

        float mx = -1e30f;
#pragma unroll
        for (int r = 0; r < 16; r++) {
            int key = (r & 3) + 8 * (r >> 2) + 4 * hh;
            float pv = s[r] + pl[kt + key];
            s[r] = pv;
            mx = fmaxf(mx, pv);
        }
        mx = fmaxf(mx, __shfl_xor(mx, 32));

        if (!__all(mx - m_run <= 11.5f)) {     // defer-max (T13, log2 domain)
            float mnew = fmaxf(m_run, mx);
            float f = __builtin_amdgcn_exp2f(m_run - mnew);
            l_run *= f;
#pragma unroll
            for (int r = 0; r < 16; r++) { o0[r] *= f; o1[r] *= f; }
            m_run = mnew;
        }

        float sum = 0.f;
#pragma unroll
        for (int r = 0; r < 16; r++) {
            s[r] = __builtin_amdgcn_exp2f(s[r] - m_run);
            sum += s[r];
        }
        sum += __shfl_xor(sum, 32);
        l_run += sum;

        union U8 { unsigned int u[4]; short8 v; } B1, B2;
#pragma unroll
        for (int t = 0; t < 4; t++) {
            B1.u[t] = cvt_pk_bf16(s[2 * t], s[2 * t + 1]);
            B2.u[t] = cvt_pk_bf16(s[8 + 2 * t], s[9 + 2 * t]);
        }

        const int vsw = c & 3;
        short8 va00 = *(const short8*)(Vb[cur] + c * 32 + ((hh ^ vsw) * 8));
        short8 va01 = *(const short8*)(Vb[cur] + c * 32 + (((2 + hh) ^ vsw) * 8));
        short8 va10 = *(const short8*)(Vb[cur] + (c + 32) * 32 + ((hh ^ vsw) * 8));
        short8 va11 = *(const short8*)(Vb[cur] + (c + 32) * 32 + (((2 + hh) ^ vsw) * 8));

        o0 = __builtin_amdgcn_mfma_f32_32x32x16_bf16(va00, B1.v, o0, 0, 0, 0);
        o0 = __builtin_amdgcn_mfma_f32_32x32x16_bf16(va01, B2.v, o0, 0, 0, 0);
        o1 = __builtin_amdgcn_mfma_f32_32x32x16_bf16(va10, B1.v, o1, 0, 0, 0);
        o1 = __builtin_amdgcn_mfma_f32_32x32x16_bf16(va11, B2.v, o1, 0, 0, 0);

        cur ^= 1;
    }

    float inv = 1.f / l_run;
    unsigned short* yr = y + (nb + q0 + c) * 1024 + h * 64;
#pragma unroll
    for (int a = 0; a < 4; a++) {
        int d0 = 8 * a + 4 * hh;
        *(unsigned int*)(yr + d0)      = cvt_pk_bf16(o0[4 * a] * inv, o0[4 * a + 1] * inv);
        *(unsigned int*)(yr + d0 + 2)  = cvt_pk_bf16(o0[4 * a + 2] * inv, o0[4 * a + 3] * inv);
        *(unsigned int*)(yr + 32 + d0)     = cvt_pk_bf16(o1[4 * a] * inv, o1[4 * a + 1] * inv);
        *(unsigned int*)(yr + 32 + d0 + 2) = cvt_pk_bf16(o1[4 * a + 2] * inv, o1[4 * a + 3] * inv);
    }
}

// --------------------------------------------------------------------------
__global__ __launch_bounds__(256)
void zcrms_kernel(const float* __restrict__ x, const float* __restrict__ g,
                  unsigned short* __restrict__ hn)
{
    __shared__ float red[8];
    const long row = blockIdx.x;
    const int tid = threadIdx.x;
    const float* xr = x + row * 1024;
    float4 v = *(const float4*)(xr + tid * 4);
    float s = v.x + v.y + v.z + v.w;
#pragma unroll
    for (int m = 32; m; m >>= 1) s += __shfl_xor(s, m);
    const int lane = tid & 63, wid = tid >> 6;
    if (lane == 0) red[wid] = s;
    __syncthreads();
    float mean = (red[0] + red[1] + red[2] + red[3]) * (1.f / 1024.f);
    float c0 = v.x - mean, c1 = v.y - mean, c2 = v.z - mean, c3 = v.w - mean;
    float s2 = c0 * c0 + c1 * c1 + c2 * c2 + c3 * c3;
#pragma unroll
    for (int m = 32; m; m >>= 1) s2 += __shfl_xor(s2, m);
    if (lane == 0) red[4 + wid] = s2;
    __syncthreads();
    float rinv = rsqrtf((red[4] + red[5] + red[6] + red[7]) * (1.f / 1024.f) + 1e-8f);
    const float* gr = g + tid * 4;
    unsigned int lo = (unsigned int)f2b(c0 * rinv * gr[0]) | ((unsigned int)f2b(c1 * rinv * gr[1]) << 16);
    unsigned int hi = (unsigned int)f2b(c2 * rinv * gr[2]) | ((unsigned int)f2b(c3 * rinv * gr[3]) << 16);
    uint2 u; u.x = lo; u.y = hi;
    *(uint2*)(hn + row * 1024 + tid * 4) = u;
}

__global__ __launch_bounds__(1024)
void embed_kernel(const float* __restrict__ patches, const float* __restrict__ W,
                  const float* __restrict__ bias, float* __restrict__ x,
                  unsigned short* __restrict__ xpad)
{
    __shared__ float sp[8][75];
    const long r0 = (long)blockIdx.x * 8;
    const int tid = threadIdx.x;
    for (int i = tid; i < 600; i += 1024) sp[i / 75][i % 75] = patches[r0 * 75 + i];
    __syncthreads();
    float acc[8];
    float bb = bias[tid];
#pragma unroll
    for (int j = 0; j < 8; j++) acc[j] = bb;
    for (int p = 0; p < 75; p++) {
        float w = W[p * 1024 + tid];
#pragma unroll
        for (int j = 0; j < 8; j++) acc[j] += sp[j][p] * w;
    }
#pragma unroll
    for (int j = 0; j < 8; j++) {
        long r = r0 + j;
        x[r * 1024 + tid] = acc[j];
        long bb2 = r >> 10, n = r & 1023;
        xpad[(bb2 * 1028 + n + 2) * 1024 + tid] = f2b(acc[j]);
    }
}

__global__ void rope_table_kernel(float* __restrict__ tab)
{
    int idx = blockIdx.x * 256 + threadIdx.x;   // 32768
    int n = idx >> 5, i = idx & 31;
    float inv = powf(10000.0f, -(float)i * (1.0f / 32.0f));
    float ang = (float)n * inv;
    tab[idx] = cosf(ang);
    tab[32768 + idx] = sinf(ang);
}

__global__ __launch_bounds__(256)
void conv3_kernel(const unsigned short* __restrict__ h2, const float* __restrict__ w3,
                  const float* __restrict__ b3, float* __restrict__ logits)
{
    const long row = (long)blockIdx.x * 4 + (threadIdx.x >> 6);
    const int lane = threadIdx.x & 63;
    const unsigned short* hr = h2 + row * 256;
    float s = 0.f;
#pragma unroll
    for (int t = 0; t < 4; t++) s += b2f(hr[lane + t * 64]) * w3[lane + t * 64];
#pragma unroll
    for (int m = 32; m; m >>= 1) s += __shfl_xor(s, m);
    if (lane == 0) logits[row] = s + b3[0];
}

__global__ __launch_bounds__(256)
void winmax_kernel(const float* __restrict__ logits, float* __restrict__ win)
{
    __shared__ float red[4];
    const int b = blockIdx.x, tid = threadIdx.x;
    float m = -1e30f;
    for (int i = tid; i < 1024; i += 256) m = fmaxf(m, logits[b * 1024 + i]);
#pragma unroll
    for (int k = 32; k; k >>= 1) m = fmaxf(m, __shfl_xor(m, k));
    if ((tid & 63) == 0) red[tid >> 6] = m;
    __syncthreads();
    if (tid == 0) win[b] = fmaxf(fmaxf(red[0], red[1]), fmaxf(red[2], red[3]));
}

// f32 (K,Nc) -> bf16 (Nc,K), batched over z
__global__ __launch_bounds__(256)
void wtrans_kernel(const float* __restrict__ in, unsigned short* __restrict__ out,
                   int K, int Nc)
{
    __shared__ float tile[32][33];
    const long base = (long)blockIdx.z * K * Nc;
    const int k0 = blockIdx.y * 32, n0 = blockIdx.x * 32;
    const int tx = threadIdx.x & 31, ty = threadIdx.x >> 5;
#pragma unroll
    for (int r = ty; r < 32; r += 8) tile[r][tx] = in[base + (long)(k0 + r) * Nc + n0 + tx];
    __syncthreads();
#pragma unroll
    for (int r = ty; r < 32; r += 8) out[base + (long)(n0 + r) * K + k0 + tx] = f2b(tile[tx][r]);
}

// (Co,Ci,Kw) f32 -> [dk][co][ci] bf16
__global__ void wconv_tap_kernel(const float* __restrict__ in, unsigned short* __restrict__ out,
                                 int CI, int KW, int CO, long total)
{
    long idx = (long)blockIdx.x * 256 + threadIdx.x;
    if (idx >= total) return;
    int ci = (int)(idx % CI);
    long t = idx / CI;
    int co = (int)(t % CO);
    int dk = (int)(t / CO);
    out[idx] = f2b(in[((long)co * CI + ci) * KW + dk]);
}

// ---------------------------------------------------------------------------
extern "C" void kernel_launch(void* const* d_in, const int* in_sizes, int n_in,
                              void* d_out, int out_size, void* d_ws, size_t ws_size,
                              hipStream_t stream)
{
    (void)in_sizes; (void)n_in; (void)out_size; (void)ws_size;
    const float* patches = (const float*)d_in[0];
    const float* embed_w = (const float*)d_in[1];
    const float* embed_b = (const float*)d_in[2];
    const float* bd_w1 = (const float*)d_in[3];
    const float* bd_b1 = (const float*)d_in[4];
    const float* bd_w2 = (const float*)d_in[5];
    const float* bd_b2 = (const float*)d_in[6];
    const float* bd_w3 = (const float*)d_in[7];
    const float* bd_b3 = (const float*)d_in[8];
    const float* norm_g = (const float*)d_in[9];
    const float* qkv_w = (const float*)d_in[10];
    const float* qkv_b = (const float*)d_in[11];
    const float* out_w = (const float*)d_in[12];
    const float* out_b = (const float*)d_in[13];
    const float* gate_w = (const float*)d_in[14];
    const float* gate_b = (const float*)d_in[15];

    char* p = (char*)d_ws;
    auto alloc = [&](size_t bytes) { char* r = p; p += (bytes + 255) & ~(size_t)255; return r; };
    unsigned short* WQ   = (unsigned short*)alloc(3ll * 3072 * 1024 * 2);
    unsigned short* WO   = (unsigned short*)alloc(3ll * 1024 * 1024 * 2);
    unsigned short* WG   = (unsigned short*)alloc(3ll * 1024 * 1024 * 2);
    unsigned short* W1S  = (unsigned short*)alloc(5ll * 512 * 1024 * 2);
    unsigned short* W2S  = (unsigned short*)alloc(3ll * 256 * 512 * 2);
    unsigned short* XPAD = (unsigned short*)alloc(4ll * 1028 * 1024 * 2);
    unsigned short* H1P  = (unsigned short*)alloc(4ll * 1026 * 512 * 2);
    unsigned short* H2   = (unsigned short*)alloc(4ll * 1024 * 256 * 2);
    float*          X    = (float*)alloc(4ll * 1024 * 1024 * 4);
    unsigned short* HN   = (unsigned short*)alloc(4096ll * 1024 * 2);
    unsigned short* QKV  = (unsigned short*)alloc(4096ll * 3072 * 2);
    unsigned short* YATT = (unsigned short*)alloc(4096ll * 1024 * 2);
    float*          LOGI = (float*)alloc(4096 * 4);
    float*          ROPE = (float*)alloc(65536 * 4);
    // VTP (B,H,64,1024) bf16 = 8MB aliased onto XPAD (conv pipeline done first)
    unsigned short* VT   = XPAD;

    hipMemsetAsync(XPAD, 0, 4ll * 1028 * 1024 * 2, stream);
    hipMemsetAsync(H1P, 0, 4ll * 1026 * 512 * 2, stream);

    wtrans_kernel<<<dim3(96, 32, 3), 256, 0, stream>>>(qkv_w, WQ, 1024, 3072);
    wtrans_kernel<<<dim3(32, 32, 3), 256, 0, stream>>>(out_w, WO, 1024, 1024);
    wtrans_kernel<<<dim3(32, 32, 3), 256, 0, stream>>>(gate_w, WG, 1024, 1024);
    wconv_tap_kernel<<<10240, 256, 0, stream>>>(bd_w1, W1S, 1024, 5, 512, 5ll * 512 * 1024);
    wconv_tap_kernel<<<1536, 256, 0, stream>>>(bd_w2, W2S, 512, 3, 256, 3ll * 256 * 512);
    rope_table_kernel<<<128, 256, 0, stream>>>(ROPE);
    embed_kernel<<<512, 1024, 0, stream>>>(patches, embed_w, embed_b, X, XPAD);

    conv_gemm<5, 1024><<<dim3(8, 8, 4), 256, 0, stream>>>(XPAD, 1028ll * 1024, W1S, 512, bd_b1,
                                                          H1P, 1026ll * 512, 512, 1);
    conv_gemm<3, 512><<<dim3(4, 8, 4), 256, 0, stream>>>(H1P, 1026ll * 512, W2S, 256, bd_b2,
                                                         H2, 1024ll * 256, 256, 0);
    conv3_kernel<<<1024, 256, 0, stream>>>(H2, bd_w3, bd_b3, LOGI);
    winmax_kernel<<<4, 256, 0, stream>>>(LOGI, (float*)d_out + 4194304);

    for (int l = 0; l < 3; l++) {
        zcrms_kernel<<<4096, 256, 0, stream>>>(X, norm_g + l * 1024, HN);
        qkv_gemm<<<dim3(24, 32), 256, 0, stream>>>(HN, WQ + (long)l * 3072 * 1024,
                                                   qkv_b + l * 3072, QKV, VT, ROPE);
        attn_kernel<<<dim3(64, 8), 256, 0, stream>>>(QKV, VT, LOGI, YATT);
        if (l < 2)
            fused_og<0><<<dim3(8, 32), 256, 0, stream>>>(YATT, WO + (long)l * 1024 * 1024, out_b + l * 1024,
                                                         HN, WG + (long)l * 1024 * 1024, gate_b + l * 1024,
                                                         X, nullptr);
        else
            fused_og<1><<<dim3(8, 32), 256, 0, stream>>>(YATT, WO + (long)l * 1024 * 1024, out_b + l * 1024,
                                                         HN, WG + (long)l * 1024 * 1024, gate_b + l * 1024,
                                                         X, (float*)d_out);
    }
}

// Round 8
// 513.930 us; speedup vs baseline: 1.1278x; 1.0159x over previous
//
#include <hip/hip_runtime.h>
#include <stdint.h>
#include <math.h>

typedef __attribute__((ext_vector_type(8))) short short8;
typedef __attribute__((ext_vector_type(4))) float f32x4;
typedef __attribute__((ext_vector_type(16))) float f32x16;

__device__ __forceinline__ float b2f(unsigned short u) {
    union { unsigned int i; float f; } v; v.i = ((unsigned int)u) << 16; return v.f;
}
__device__ __forceinline__ unsigned short f2b(float f) {
    union { float f; unsigned int i; } v; v.f = f;
    unsigned int r = v.i + 0x7fffu + ((v.i >> 16) & 1u);
    return (unsigned short)(r >> 16);
}
__device__ __forceinline__ unsigned int cvt_pk_bf16(float lo, float hi) {
    unsigned int r;
    asm("v_cvt_pk_bf16_f32 %0, %1, %2" : "=v"(r) : "v"(lo), "v"(hi));
    return r;
}

__device__ __forceinline__ void gload_lds16(const void* g, void* l) {
    __builtin_amdgcn_global_load_lds((__attribute__((address_space(1))) void*)g,
                                     (__attribute__((address_space(3))) void*)l,
                                     16, 0, 0);
}

// ---------------------------------------------------------------------------
// qkv GEMM (128x128, BK=64 single-buffered — half the barriers of BK=32).
// LDS rows 64 elems (128B) with source-side XOR swizzle (chunk j stored at
// j^(row&7)) so fragment ds_read_b128 is conflict-free (rule #21: linear LDS
// dest for global_load_lds + inverse-swizzled SOURCE + swizzled read).
// Fused RoPE epilogue (Q pre-scaled by 0.125*log2e) + fused V->VT store.
// ---------------------------------------------------------------------------
__global__ __launch_bounds__(256, 3)
void qkv_gemm(const unsigned short* __restrict__ A,
              const unsigned short* __restrict__ Bw,
              const float* __restrict__ bias,
              unsigned short* __restrict__ Cb,
              unsigned short* __restrict__ vt,
              const float* __restrict__ rope)
{
    __shared__ __align__(16) unsigned short As[128 * 64];
    __shared__ __align__(16) unsigned short Bs[128 * 64];
    const int tid = threadIdx.x;
    const int lane = tid & 63, wid = tid >> 6;
    const int wr = wid >> 1, wc = wid & 1;
    const long brow = (long)blockIdx.y * 128;
    const long bcol = (long)blockIdx.x * 128;

    // staging: instruction i covers rows i*32..i*32+31; thread: row tid>>3,
    // LDS chunk pos tid&7, global source chunk (tid&7)^(row&7)
    const int srow = tid >> 3;                       // 0..31
    const int schk = (tid & 7) ^ (srow & 7);
    const unsigned short* gA = A + (brow + srow) * 1024 + schk * 8;
    const unsigned short* gB = Bw + (bcol + srow) * 1024 + schk * 8;
    unsigned short* lA = As + tid * 8;
    unsigned short* lB = Bs + tid * 8;

    f32x4 acc[4][4] = {};
    const int fr = lane & 15, g = lane >> 4;
    const int fsw = fr & 7;

    for (int kk = 0; kk < 1024; kk += 64) {
#pragma unroll
        for (int i = 0; i < 4; i++) {
            gload_lds16(gA + (long)i * 32 * 1024 + kk, lA + i * 2048);
            gload_lds16(gB + (long)i * 32 * 1024 + kk, lB + i * 2048);
        }
        __syncthreads();                 // drains stage (vmcnt 0) + barrier
        short8 af[4][2], bf[4][2];
#pragma unroll
        for (int m = 0; m < 4; m++) {
            int r = wr * 64 + m * 16 + fr;
#pragma unroll
            for (int k2 = 0; k2 < 2; k2++)
                af[m][k2] = *(const short8*)(As + r * 64 + (((k2 * 4 + g) ^ fsw) * 8));
        }
#pragma unroll
        for (int n = 0; n < 4; n++) {
            int r = wc * 64 + n * 16 + fr;
#pragma unroll
            for (int k2 = 0; k2 < 2; k2++)
                bf[n][k2] = *(const short8*)(Bs + r * 64 + (((k2 * 4 + g) ^ fsw) * 8));
        }
#pragma unroll
        for (int m = 0; m < 4; m++)
#pragma unroll
            for (int n = 0; n < 4; n++) {
                acc[m][n] = __builtin_amdgcn_mfma_f32_16x16x32_bf16(af[m][0], bf[n][0], acc[m][n], 0, 0, 0);
                acc[m][n] = __builtin_amdgcn_mfma_f32_16x16x32_bf16(af[m][1], bf[n][1], acc[m][n], 0, 0, 0);
            }
        __syncthreads();
    }

    const int fq = g * 4;
    if (bcol < 2048) {
        // Q/K blocks: bias + RoPE (+Q scale), bf16 store into QKV
#pragma unroll
        for (int m = 0; m < 4; m++) {
#pragma unroll
            for (int n = 0; n < 4; n++) {
#pragma unroll
                for (int j = 0; j < 4; j++) {
                    long row = brow + wr * 64 + m * 16 + fq + j;
                    int col = (int)bcol + wc * 64 + n * 16 + fr;
                    float v = acc[m][n][j] + bias[col];
                    float part = __shfl_xor(v, 1);   // partner col (d^1), same row
                    int d = col & 63;
                    int i2 = d >> 1;
                    int ntok = (int)(row & 1023);
                    float cc = rope[ntok * 32 + i2];
                    float ss = rope[32768 + ntok * 32 + i2];
                    v = (d & 1) ? (part * ss + v * cc) : (v * cc - part * ss);
                    if (col < 1024) v *= 0.18033688011112042f;   // 0.125*log2(e)
                    Cb[row * 3072 + col] = f2b(v);
                }
            }
        }
    } else {
        // V blocks: bias, store transposed+key-permuted into VT.
        const int fqp = (fq == 4) ? 8 : (fq == 8) ? 4 : fq;
        const int b = (int)(brow >> 10);
        const int rb = (int)(brow & 1023);
        unsigned short* vtb = vt + ((long)b << 20);
#pragma unroll
        for (int m = 0; m < 4; m++) {
            int ntok = rb + wr * 64 + m * 16 + fqp;
#pragma unroll
            for (int n = 0; n < 4; n++) {
                int hd = (int)bcol - 2048 + wc * 64 + n * 16 + fr;   // h*64+d
                float bb = bias[2048 + hd];
                uint2 u;
                u.x = cvt_pk_bf16(acc[m][n][0] + bb, acc[m][n][1] + bb);
                u.y = cvt_pk_bf16(acc[m][n][2] + bb, acc[m][n][3] + bb);
                *(uint2*)(vtb + (long)hd * 1024 + ntok) = u;
            }
        }
    }
}

// ---------------------------------------------------------------------------
// Tap-accumulation conv-as-GEMM (unchanged).
// ---------------------------------------------------------------------------
template<int KW, int CI>
__global__ __launch_bounds__(256)
void conv_gemm(const unsigned short* __restrict__ A, long sAb,
               const unsigned short* __restrict__ Bw, int CO,
               const float* __restrict__ bias,
               unsigned short* __restrict__ C, long sCb, int ldc, int crow_off)
{
    __shared__ __align__(16) unsigned short As[2][144 * 32];
    __shared__ __align__(16) unsigned short Bs[2][KW * 64 * 32];
    const int tid = threadIdx.x, lane = tid & 63, wid = tid >> 6;
    const int wr = wid >> 1, wc = wid & 1;
    const int z = blockIdx.z;
    const long brow = (long)blockIdx.y * 128;
    const long bcol = (long)blockIdx.x * 64;
    const unsigned short* Ab = A + z * sAb + brow * CI;
    const int srow = tid >> 2, scol = (tid & 3) * 8;

    f32x4 acc[4][2] = {};

    auto STAGE = [&](int buf, int kk) {
#pragma unroll
        for (int o = 0; o < 2; o++)
            gload_lds16(Ab + (long)(o * 64 + srow) * CI + kk + scol,
                        As[buf] + (o * 64 + wid * 16) * 32);
        if (wid == 0)
            gload_lds16(Ab + (long)(128 + srow) * CI + kk + scol,
                        As[buf] + 128 * 32);
#pragma unroll
        for (int dk = 0; dk < KW; dk++)
            gload_lds16(Bw + ((long)dk * CO + bcol + srow) * CI + kk + scol,
                        Bs[buf] + (dk * 64 + wid * 16) * 32);
    };

    STAGE(0, 0);
    const int fr = lane & 15, fk = (lane >> 4) * 8;
    int cur = 0;
    for (int kk = 0; kk < CI; kk += 32) {
        __syncthreads();
        if (kk + 32 < CI) STAGE(cur ^ 1, kk + 32);
        short8 bfr[KW][2];
#pragma unroll
        for (int dk = 0; dk < KW; dk++)
#pragma unroll
            for (int n = 0; n < 2; n++)
                bfr[dk][n] = *(const short8*)(Bs[cur] + (dk * 64 + wc * 32 + n * 16 + fr) * 32 + fk);
#pragma unroll
        for (int m = 0; m < 4; m++) {
#pragma unroll
            for (int dk = 0; dk < KW; dk++) {
                short8 af = *(const short8*)(As[cur] + (wr * 64 + m * 16 + fr + dk) * 32 + fk);
#pragma unroll
                for (int n = 0; n < 2; n++)
                    acc[m][n] = __builtin_amdgcn_mfma_f32_16x16x32_bf16(af, bfr[dk][n], acc[m][n], 0, 0, 0);
            }
        }
        cur ^= 1;
    }

    const int fq = (lane >> 4) * 4;
#pragma unroll
    for (int m = 0; m < 4; m++) {
#pragma unroll
        for (int n = 0; n < 2; n++) {
#pragma unroll
            for (int j = 0; j < 4; j++) {
                long row = brow + wr * 64 + m * 16 + fq + j;
                int col = (int)bcol + wc * 32 + n * 16 + fr;
                float v = acc[m][n][j] + bias[col];
                v = v / (1.f + __expf(-v));    // silu
                C[z * sCb + (crow_off + row) * ldc + col] = f2b(v);
            }
        }
    }
}

// ---------------------------------------------------------------------------
// Fused out-proj + gate GEMMs + residual epilogue (unchanged).
// ---------------------------------------------------------------------------
template<int LAST>
__global__ __launch_bounds__(256)
void fused_og(const unsigned short* __restrict__ A1, const unsigned short* __restrict__ B1,
              const float* __restrict__ b1,
              const unsigned short* __restrict__ A2, const unsigned short* __restrict__ B2,
              const float* __restrict__ b2,
              float* __restrict__ X, float* __restrict__ OUT)
{
    __shared__ __align__(16) unsigned short S[2][4][128 * 32];
    const int tid = threadIdx.x, lane = tid & 63, wid = tid >> 6;
    const int wr = wid >> 1, wc = wid & 1;
    const long brow = (long)blockIdx.y * 128;
    const long bcol = (long)blockIdx.x * 128;
    const int srow = tid >> 2, scol = (tid & 3) * 8;

    const unsigned short* g0 = A1 + (brow + srow) * 1024 + scol;
    const unsigned short* g1 = B1 + (bcol + srow) * 1024 + scol;
    const unsigned short* g2 = A2 + (brow + srow) * 1024 + scol;
    const unsigned short* g3 = B2 + (bcol + srow) * 1024 + scol;

    f32x4 acc1[4][4] = {}, acc2[4][4] = {};

    auto STAGE = [&](int buf, int kk) {
#pragma unroll
        for (int o = 0; o < 2; o++) {
            gload_lds16(g0 + (long)o * 65536 + kk, S[buf][0] + (o * 64 + wid * 16) * 32);
            gload_lds16(g1 + (long)o * 65536 + kk, S[buf][1] + (o * 64 + wid * 16) * 32);
            gload_lds16(g2 + (long)o * 65536 + kk, S[buf][2] + (o * 64 + wid * 16) * 32);
            gload_lds16(g3 + (long)o * 65536 + kk, S[buf][3] + (o * 64 + wid * 16) * 32);
        }
    };

    STAGE(0, 0);
    const int fr = lane & 15, fk = (lane >> 4) * 8;
    int cur = 0;
    for (int kk = 0; kk < 1024; kk += 32) {
        __syncthreads();
        if (kk + 32 < 1024) STAGE(cur ^ 1, kk + 32);
        {
            short8 af[4], bf[4];
#pragma unroll
            for (int m = 0; m < 4; m++)
                af[m] = *(const short8*)(S[cur][0] + (wr * 64 + m * 16 + fr) * 32 + fk);
#pragma unroll
            for (int n = 0; n < 4; n++)
                bf[n] = *(const short8*)(S[cur][1] + (wc * 64 + n * 16 + fr) * 32 + fk);
#pragma unroll
            for (int m = 0; m < 4; m++)
#pragma unroll
                for (int n = 0; n < 4; n++)
                    acc1[m][n] = __builtin_amdgcn_mfma_f32_16x16x32_bf16(af[m], bf[n], acc1[m][n], 0, 0, 0);
        }
        {
            short8 af[4], bf[4];
#pragma unroll
            for (int m = 0; m < 4; m++)
                af[m] = *(const short8*)(S[cur][2] + (wr * 64 + m * 16 + fr) * 32 + fk);
#pragma unroll
            for (int n = 0; n < 4; n++)
                bf[n] = *(const short8*)(S[cur][3] + (wc * 64 + n * 16 + fr) * 32 + fk);
#pragma unroll
            for (int m = 0; m < 4; m++)
#pragma unroll
                for (int n = 0; n < 4; n++)
                    acc2[m][n] = __builtin_amdgcn_mfma_f32_16x16x32_bf16(af[m], bf[n], acc2[m][n], 0, 0, 0);
        }
        cur ^= 1;
    }

    const int fq = (lane >> 4) * 4;
#pragma unroll
    for (int m = 0; m < 4; m++) {
#pragma unroll
        for (int n = 0; n < 4; n++) {
#pragma unroll
            for (int j = 0; j < 4; j++) {
                long row = brow + wr * 64 + m * 16 + fq + j;
                int col = (int)bcol + wc * 64 + n * 16 + fr;
                float v1 = acc1[m][n][j] + b1[col];
                float v2 = acc2[m][n][j] + b2[col];
                long idx = row * 1024 + col;
                float r = X[idx] + v1 / (1.f + __expf(-v2));
                if (LAST) OUT[idx] = r; else X[idx] = r;
            }
        }
    }
}

// ---------------------------------------------------------------------------
// Flash attention v5: KVBLK=64 (one stage+barrier pair per 64 keys, two
// 32-key softmax/PV sub-blocks per phase). Swapped-QK^T 32x32 + transposed
// PV; exp2-domain softmax; K/V LDS-staged dbuf with pre-swizzled source.
// ---------------------------------------------------------------------------
__global__ __launch_bounds__(256)
void attn_kernel(const unsigned short* __restrict__ qkv,
                 const unsigned short* __restrict__ vt,   // VTP (key-permuted)
                 const float* __restrict__ plog,
                 unsigned short* __restrict__ y)
{
    __shared__ __align__(16) unsigned short Kb[2][64 * 64];
    __shared__ __align__(16) unsigned short Vb[2][64 * 64];
    __shared__ float pl[1024];

    const int bh = blockIdx.x;
    const int qt = blockIdx.y;
    const int b = bh >> 4, h = bh & 15;
    const int tid = threadIdx.x, lane = tid & 63, wid = tid >> 6;
    const int c = lane & 31;
    const int hh = lane >> 5;

    const long nb = (long)b * 1024;
    const unsigned short* qbase = qkv + nb * 3072 + h * 64;
    const unsigned short* kbase = qbase + 1024;
    const unsigned short* vtb = vt + (long)bh * 65536;

    for (int i = tid; i < 1024; i += 256) pl[i] = plog[b * 1024 + i] * 1.4426950408889634f;

    // staging: thread row tid>>3, LDS chunk tid&7, source chunk ^(row&7)
    const int srow = tid >> 3;                       // 0..31
    const int schk = (tid & 7) ^ (srow & 7);
    const unsigned short* gk = kbase + (long)srow * 3072 + schk * 8;
    const unsigned short* gv = vtb + (long)srow * 1024 + schk * 8;

    auto STAGE = [&](int buf, int kt) {
#pragma unroll
        for (int i = 0; i < 2; i++) {
            gload_lds16(gk + (long)(kt + i * 32) * 3072, &Kb[buf][i * 2048 + tid * 8]);
            gload_lds16(gv + (long)i * 32 * 1024 + kt, &Vb[buf][i * 2048 + tid * 8]);
        }
    };

    const int q0 = qt * 128 + wid * 32;
    short8 qf[4];
#pragma unroll
    for (int d = 0; d < 4; d++)
        qf[d] = *(const short8*)(qbase + (long)(q0 + c) * 3072 + d * 16 + hh * 8);

    float m_run = -1e30f, l_run = 0.f;
    f32x16 o0 = {}, o1 = {};
    const int csw = c & 7;

    STAGE(0, 0);
    int cur = 0;
    for (int kt = 0; kt < 1024; kt += 64) {
        __syncthreads();                 // tile[cur] ready (drains vmcnt)
        if (kt + 64 < 1024) STAGE(cur ^ 1, kt + 64);

#pragma unroll
        for (int sb = 0; sb < 2; sb++) {
            // K fragments: rows sb*32 + c, global chunk (2d+hh)
            short8 kf[4];
#pragma unroll
            for (int d = 0; d < 4; d++)
                kf[d] = *(const short8*)(&Kb[cur][(sb * 32 + c) * 64 + (((2 * d + hh) ^ csw) * 8)]);

            f32x16 s = {};
#pragma unroll
            for (int d = 0; d < 4; d++)
                s = __builtin_amdgcn_mfma_f32_32x32x16_bf16(kf[d], qf[d], s, 0, 0, 0);

            float mx = -1e30f;
#pragma unroll
            for (int r = 0; r < 16; r++) {
                int key = (r & 3) + 8 * (r >> 2) + 4 * hh;
                float pv = s[r] + pl[kt + sb * 32 + key];
                s[r] = pv;
                mx = fmaxf(mx, pv);
            }
            mx = fmaxf(mx, __shfl_xor(mx, 32));

            if (!__all(mx - m_run <= 11.5f)) {     // defer-max (T13, log2 domain)
                float mnew = fmaxf(m_run, mx);
                float f = __builtin_amdgcn_exp2f(m_run - mnew);
                l_run *= f;
#pragma unroll
                for (int r = 0; r < 16; r++) { o0[r] *= f; o1[r] *= f; }
                m_run = mnew;
            }

            float sum = 0.f;
#pragma unroll
            for (int r = 0; r < 16; r++) {
                s[r] = __builtin_amdgcn_exp2f(s[r] - m_run);
                sum += s[r];
            }
            sum += __shfl_xor(sum, 32);
            l_run += sum;

            union U8 { unsigned int u[4]; short8 v; } P1, P2;
#pragma unroll
            for (int t = 0; t < 4; t++) {
                P1.u[t] = cvt_pk_bf16(s[2 * t], s[2 * t + 1]);
                P2.u[t] = cvt_pk_bf16(s[8 + 2 * t], s[9 + 2 * t]);
            }

            // V^T fragments: rows c / c+32, global chunk sb*4 + kh*2 + hh
            short8 va00 = *(const short8*)(&Vb[cur][c * 64 + (((sb * 4 + hh) ^ csw) * 8)]);
            short8 va01 = *(const short8*)(&Vb[cur][c * 64 + (((sb * 4 + 2 + hh) ^ csw) * 8)]);
            short8 va10 = *(const short8*)(&Vb[cur][(c + 32) * 64 + (((sb * 4 + hh) ^ csw) * 8)]);
            short8 va11 = *(const short8*)(&Vb[cur][(c + 32) * 64 + (((sb * 4 + 2 + hh) ^ csw) * 8)]);

            o0 = __builtin_amdgcn_mfma_f32_32x32x16_bf16(va00, P1.v, o0, 0, 0, 0);
            o0 = __builtin_amdgcn_mfma_f32_32x32x16_bf16(va01, P2.v, o0, 0, 0, 0);
            o1 = __builtin_amdgcn_mfma_f32_32x32x16_bf16(va10, P1.v, o1, 0, 0, 0);
            o1 = __builtin_amdgcn_mfma_f32_32x32x16_bf16(va11, P2.v, o1, 0, 0, 0);
        }
        cur ^= 1;
    }

    float inv = 1.f / l_run;
    unsigned short* yr = y + (nb + q0 + c) * 1024 + h * 64;
#pragma unroll
    for (int a = 0; a < 4; a++) {
        int d0 = 8 * a + 4 * hh;
        *(unsigned int*)(yr + d0)      = cvt_pk_bf16(o0[4 * a] * inv, o0[4 * a + 1] * inv);
        *(unsigned int*)(yr + d0 + 2)  = cvt_pk_bf16(o0[4 * a + 2] * inv, o0[4 * a + 3] * inv);
        *(unsigned int*)(yr + 32 + d0)     = cvt_pk_bf16(o1[4 * a] * inv, o1[4 * a + 1] * inv);
        *(unsigned int*)(yr + 32 + d0 + 2) = cvt_pk_bf16(o1[4 * a + 2] * inv, o1[4 * a + 3] * inv);
    }
}

// --------------------------------------------------------------------------
__global__ __launch_bounds__(256)
void zcrms_kernel(const float* __restrict__ x, const float* __restrict__ g,
                  unsigned short* __restrict__ hn)
{
    __shared__ float red[8];
    const long row = blockIdx.x;
    const int tid = threadIdx.x;
    const float* xr = x + row * 1024;
    float4 v = *(const float4*)(xr + tid * 4);
    float s = v.x + v.y + v.z + v.w;
#pragma unroll
    for (int m = 32; m; m >>= 1) s += __shfl_xor(s, m);
    const int lane = tid & 63, wid = tid >> 6;
    if (lane == 0) red[wid] = s;
    __syncthreads();
    float mean = (red[0] + red[1] + red[2] + red[3]) * (1.f / 1024.f);
    float c0 = v.x - mean, c1 = v.y - mean, c2 = v.z - mean, c3 = v.w - mean;
    float s2 = c0 * c0 + c1 * c1 + c2 * c2 + c3 * c3;
#pragma unroll
    for (int m = 32; m; m >>= 1) s2 += __shfl_xor(s2, m);
    if (lane == 0) red[4 + wid] = s2;
    __syncthreads();
    float rinv = rsqrtf((red[4] + red[5] + red[6] + red[7]) * (1.f / 1024.f) + 1e-8f);
    const float* gr = g + tid * 4;
    unsigned int lo = (unsigned int)f2b(c0 * rinv * gr[0]) | ((unsigned int)f2b(c1 * rinv * gr[1]) << 16);
    unsigned int hi = (unsigned int)f2b(c2 * rinv * gr[2]) | ((unsigned int)f2b(c3 * rinv * gr[3]) << 16);
    uint2 u; u.x = lo; u.y = hi;
    *(uint2*)(hn + row * 1024 + tid * 4) = u;
}

__global__ __launch_bounds__(1024)
void embed_kernel(const float* __restrict__ patches, const float* __restrict__ W,
                  const float* __restrict__ bias, float* __restrict__ x,
                  unsigned short* __restrict__ xpad)
{
    __shared__ float sp[8][75];
    const long r0 = (long)blockIdx.x * 8;
    const int tid = threadIdx.x;
    for (int i = tid; i < 600; i += 1024) sp[i / 75][i % 75] = patches[r0 * 75 + i];
    __syncthreads();
    float acc[8];
    float bb = bias[tid];
#pragma unroll
    for (int j = 0; j < 8; j++) acc[j] = bb;
    for (int p = 0; p < 75; p++) {
        float w = W[p * 1024 + tid];
#pragma unroll
        for (int j = 0; j < 8; j++) acc[j] += sp[j][p] * w;
    }
#pragma unroll
    for (int j = 0; j < 8; j++) {
        long r = r0 + j;
        x[r * 1024 + tid] = acc[j];
        long bb2 = r >> 10, n = r & 1023;
        xpad[(bb2 * 1028 + n + 2) * 1024 + tid] = f2b(acc[j]);
    }
}

__global__ void rope_table_kernel(float* __restrict__ tab)
{
    int idx = blockIdx.x * 256 + threadIdx.x;   // 32768
    int n = idx >> 5, i = idx & 31;
    float inv = powf(10000.0f, -(float)i * (1.0f / 32.0f));
    float ang = (float)n * inv;
    tab[idx] = cosf(ang);
    tab[32768 + idx] = sinf(ang);
}

__global__ __launch_bounds__(256)
void conv3_kernel(const unsigned short* __restrict__ h2, const float* __restrict__ w3,
                  const float* __restrict__ b3, float* __restrict__ logits)
{
    const long row = (long)blockIdx.x * 4 + (threadIdx.x >> 6);
    const int lane = threadIdx.x & 63;
    const unsigned short* hr = h2 + row * 256;
    float s = 0.f;
#pragma unroll
    for (int t = 0; t < 4; t++) s += b2f(hr[lane + t * 64]) * w3[lane + t * 64];
#pragma unroll
    for (int m = 32; m; m >>= 1) s += __shfl_xor(s, m);
    if (lane == 0) logits[row] = s + b3[0];
}

__global__ __launch_bounds__(256)
void winmax_kernel(const float* __restrict__ logits, float* __restrict__ win)
{
    __shared__ float red[4];
    const int b = blockIdx.x, tid = threadIdx.x;
    float m = -1e30f;
    for (int i = tid; i < 1024; i += 256) m = fmaxf(m, logits[b * 1024 + i]);
#pragma unroll
    for (int k = 32; k; k >>= 1) m = fmaxf(m, __shfl_xor(m, k));
    if ((tid & 63) == 0) red[tid >> 6] = m;
    __syncthreads();
    if (tid == 0) win[b] = fmaxf(fmaxf(red[0], red[1]), fmaxf(red[2], red[3]));
}

// f32 (K,Nc) -> bf16 (Nc,K), batched over z
__global__ __launch_bounds__(256)
void wtrans_kernel(const float* __restrict__ in, unsigned short* __restrict__ out,
                   int K, int Nc)
{
    __shared__ float tile[32][33];
    const long base = (long)blockIdx.z * K * Nc;
    const int k0 = blockIdx.y * 32, n0 = blockIdx.x * 32;
    const int tx = threadIdx.x & 31, ty = threadIdx.x >> 5;
#pragma unroll
    for (int r = ty; r < 32; r += 8) tile[r][tx] = in[base + (long)(k0 + r) * Nc + n0 + tx];
    __syncthreads();
#pragma unroll
    for (int r = ty; r < 32; r += 8) out[base + (long)(n0 + r) * K + k0 + tx] = f2b(tile[tx][r]);
}

// (Co,Ci,Kw) f32 -> [dk][co][ci] bf16
__global__ void wconv_tap_kernel(const float* __restrict__ in, unsigned short* __restrict__ out,
                                 int CI, int KW, int CO, long total)
{
    long idx = (long)blockIdx.x * 256 + threadIdx.x;
    if (idx >= total) return;
    int ci = (int)(idx % CI);
    long t = idx / CI;
    int co = (int)(t % CO);
    int dk = (int)(t / CO);
    out[idx] = f2b(in[((long)co * CI + ci) * KW + dk]);
}

// ---------------------------------------------------------------------------
extern "C" void kernel_launch(void* const* d_in, const int* in_sizes, int n_in,
                              void* d_out, int out_size, void* d_ws, size_t ws_size,
                              hipStream_t stream)
{
    (void)in_sizes; (void)n_in; (void)out_size; (void)ws_size;
    const float* patches = (const float*)d_in[0];
    const float* embed_w = (const float*)d_in[1];
    const float* embed_b = (const float*)d_in[2];
    const float* bd_w1 = (const float*)d_in[3];
    const float* bd_b1 = (const float*)d_in[4];
    const float* bd_w2 = (const float*)d_in[5];
    const float* bd_b2 = (const float*)d_in[6];
    const float* bd_w3 = (const float*)d_in[7];
    const float* bd_b3 = (const float*)d_in[8];
    const float* norm_g = (const float*)d_in[9];
    const float* qkv_w = (const float*)d_in[10];
    const float* qkv_b = (const float*)d_in[11];
    const float* out_w = (const float*)d_in[12];
    const float* out_b = (const float*)d_in[13];
    const float* gate_w = (const float*)d_in[14];
    const float* gate_b = (const float*)d_in[15];

    char* p = (char*)d_ws;
    auto alloc = [&](size_t bytes) { char* r = p; p += (bytes + 255) & ~(size_t)255; return r; };
    unsigned short* WQ   = (unsigned short*)alloc(3ll * 3072 * 1024 * 2);
    unsigned short* WO   = (unsigned short*)alloc(3ll * 1024 * 1024 * 2);
    unsigned short* WG   = (unsigned short*)alloc(3ll * 1024 * 1024 * 2);
    unsigned short* W1S  = (unsigned short*)alloc(5ll * 512 * 1024 * 2);
    unsigned short* W2S  = (unsigned short*)alloc(3ll * 256 * 512 * 2);
    unsigned short* XPAD = (unsigned short*)alloc(4ll * 1028 * 1024 * 2);
    unsigned short* H1P  = (unsigned short*)alloc(4ll * 1026 * 512 * 2);
    unsigned short* H2   = (unsigned short*)alloc(4ll * 1024 * 256 * 2);
    float*          X    = (float*)alloc(4ll * 1024 * 1024 * 4);
    unsigned short* HN   = (unsigned short*)alloc(4096ll * 1024 * 2);
    unsigned short* QKV  = (unsigned short*)alloc(4096ll * 3072 * 2);
    unsigned short* YATT = (unsigned short*)alloc(4096ll * 1024 * 2);
    float*          LOGI = (float*)alloc(4096 * 4);
    float*          ROPE = (float*)alloc(65536 * 4);
    // VTP (B,H,64,1024) bf16 = 8MB aliased onto XPAD (conv pipeline done first)
    unsigned short* VT   = XPAD;

    hipMemsetAsync(XPAD, 0, 4ll * 1028 * 1024 * 2, stream);
    hipMemsetAsync(H1P, 0, 4ll * 1026 * 512 * 2, stream);

    wtrans_kernel<<<dim3(96, 32, 3), 256, 0, stream>>>(qkv_w, WQ, 1024, 3072);
    wtrans_kernel<<<dim3(32, 32, 3), 256, 0, stream>>>(out_w, WO, 1024, 1024);
    wtrans_kernel<<<dim3(32, 32, 3), 256, 0, stream>>>(gate_w, WG, 1024, 1024);
    wconv_tap_kernel<<<10240, 256, 0, stream>>>(bd_w1, W1S, 1024, 5, 512, 5ll * 512 * 1024);
    wconv_tap_kernel<<<1536, 256, 0, stream>>>(bd_w2, W2S, 512, 3, 256, 3ll * 256 * 512);
    rope_table_kernel<<<128, 256, 0, stream>>>(ROPE);
    embed_kernel<<<512, 1024, 0, stream>>>(patches, embed_w, embed_b, X, XPAD);

    conv_gemm<5, 1024><<<dim3(8, 8, 4), 256, 0, stream>>>(XPAD, 1028ll * 1024, W1S, 512, bd_b1,
                                                          H1P, 1026ll * 512, 512, 1);
    conv_gemm<3, 512><<<dim3(4, 8, 4), 256, 0, stream>>>(H1P, 1026ll * 512, W2S, 256, bd_b2,
                                                         H2, 1024ll * 256, 256, 0);
    conv3_kernel<<<1024, 256, 0, stream>>>(H2, bd_w3, bd_b3, LOGI);
    winmax_kernel<<<4, 256, 0, stream>>>(LOGI, (float*)d_out + 4194304);

    for (int l = 0; l < 3; l++) {
        zcrms_kernel<<<4096, 256, 0, stream>>>(X, norm_g + l * 1024, HN);
        qkv_gemm<<<dim3(24, 32), 256, 0, stream>>>(HN, WQ + (long)l * 3072 * 1024,
                                                   qkv_b + l * 3072, QKV, VT, ROPE);
        attn_kernel<<<dim3(64, 8), 256, 0, stream>>>(QKV, VT, LOGI, YATT);
        if (l < 2)
            fused_og<0><<<dim3(8, 32), 256, 0, stream>>>(YATT, WO + (long)l * 1024 * 1024, out_b + l * 1024,
                                                         HN, WG + (long)l * 1024 * 1024, gate_b + l * 1024,
                                                         X, nullptr);
        else
            fused_og<1><<<dim3(8, 32), 256, 0, stream>>>(YATT, WO + (long)l * 1024 * 1024, out_b + l * 1024,
                                                         HN, WG + (long)l * 1024 * 1024, gate_b + l * 1024,
                                                         X, (float*)d_out);
    }
}

// Round 9
// 444.122 us; speedup vs baseline: 1.3051x; 1.1572x over previous
//
#include <hip/hip_runtime.h>
#include <stdint.h>
#include <math.h>

typedef __attribute__((ext_vector_type(8))) short short8;
typedef __attribute__((ext_vector_type(4))) float f32x4;
typedef __attribute__((ext_vector_type(16))) float f32x16;

__device__ __forceinline__ float b2f(unsigned short u) {
    union { unsigned int i; float f; } v; v.i = ((unsigned int)u) << 16; return v.f;
}
__device__ __forceinline__ unsigned short f2b(float f) {
    union { float f; unsigned int i; } v; v.f = f;
    unsigned int r = v.i + 0x7fffu + ((v.i >> 16) & 1u);
    return (unsigned short)(r >> 16);
}
__device__ __forceinline__ unsigned int cvt_pk_bf16(float lo, float hi) {
    unsigned int r;
    asm("v_cvt_pk_bf16_f32 %0, %1, %2" : "=v"(r) : "v"(lo), "v"(hi));
    return r;
}

__device__ __forceinline__ void gload_lds16(const void* g, void* l) {
    __builtin_amdgcn_global_load_lds((__attribute__((address_space(1))) void*)g,
                                     (__attribute__((address_space(3))) void*)l,
                                     16, 0, 0);
}

// ---------------------------------------------------------------------------
// qkv GEMM (128x128, BK=64, source-swizzled — round-8 proven) with fused
// RoPE epilogue + fused V->VT store. Grid (32 rows, 24 cols): linear id % 8
// = row-panel -> all col-tiles of a panel share one XCD's L2.
// ---------------------------------------------------------------------------
__global__ __launch_bounds__(256, 3)
void qkv_gemm(const unsigned short* __restrict__ A,
              const unsigned short* __restrict__ Bw,
              const float* __restrict__ bias,
              unsigned short* __restrict__ Cb,
              unsigned short* __restrict__ vt,
              const float* __restrict__ rope)
{
    __shared__ __align__(16) unsigned short As[128 * 64];
    __shared__ __align__(16) unsigned short Bs[128 * 64];
    const int tid = threadIdx.x;
    const int lane = tid & 63, wid = tid >> 6;
    const int wr = wid >> 1, wc = wid & 1;
    const long brow = (long)blockIdx.x * 128;   // row-major grid (XCD pin)
    const long bcol = (long)blockIdx.y * 128;

    const int srow = tid >> 3;                       // 0..31
    const int schk = (tid & 7) ^ (srow & 7);
    const unsigned short* gA = A + (brow + srow) * 1024 + schk * 8;
    const unsigned short* gB = Bw + (bcol + srow) * 1024 + schk * 8;
    unsigned short* lA = As + tid * 8;
    unsigned short* lB = Bs + tid * 8;

    f32x4 acc[4][4] = {};
    const int fr = lane & 15, g = lane >> 4;
    const int fsw = fr & 7;

    for (int kk = 0; kk < 1024; kk += 64) {
#pragma unroll
        for (int i = 0; i < 4; i++) {
            gload_lds16(gA + (long)i * 32 * 1024 + kk, lA + i * 2048);
            gload_lds16(gB + (long)i * 32 * 1024 + kk, lB + i * 2048);
        }
        __syncthreads();
        short8 af[4][2], bf[4][2];
#pragma unroll
        for (int m = 0; m < 4; m++) {
            int r = wr * 64 + m * 16 + fr;
#pragma unroll
            for (int k2 = 0; k2 < 2; k2++)
                af[m][k2] = *(const short8*)(As + r * 64 + (((k2 * 4 + g) ^ fsw) * 8));
        }
#pragma unroll
        for (int n = 0; n < 4; n++) {
            int r = wc * 64 + n * 16 + fr;
#pragma unroll
            for (int k2 = 0; k2 < 2; k2++)
                bf[n][k2] = *(const short8*)(Bs + r * 64 + (((k2 * 4 + g) ^ fsw) * 8));
        }
#pragma unroll
        for (int m = 0; m < 4; m++)
#pragma unroll
            for (int n = 0; n < 4; n++) {
                acc[m][n] = __builtin_amdgcn_mfma_f32_16x16x32_bf16(af[m][0], bf[n][0], acc[m][n], 0, 0, 0);
                acc[m][n] = __builtin_amdgcn_mfma_f32_16x16x32_bf16(af[m][1], bf[n][1], acc[m][n], 0, 0, 0);
            }
        __syncthreads();
    }

    const int fq = g * 4;
    if (bcol < 2048) {
#pragma unroll
        for (int m = 0; m < 4; m++) {
#pragma unroll
            for (int n = 0; n < 4; n++) {
#pragma unroll
                for (int j = 0; j < 4; j++) {
                    long row = brow + wr * 64 + m * 16 + fq + j;
                    int col = (int)bcol + wc * 64 + n * 16 + fr;
                    float v = acc[m][n][j] + bias[col];
                    float part = __shfl_xor(v, 1);
                    int d = col & 63;
                    int i2 = d >> 1;
                    int ntok = (int)(row & 1023);
                    float cc = rope[ntok * 32 + i2];
                    float ss = rope[32768 + ntok * 32 + i2];
                    v = (d & 1) ? (part * ss + v * cc) : (v * cc - part * ss);
                    if (col < 1024) v *= 0.18033688011112042f;   // 0.125*log2(e)
                    Cb[row * 3072 + col] = f2b(v);
                }
            }
        }
    } else {
        const int fqp = (fq == 4) ? 8 : (fq == 8) ? 4 : fq;
        const int b = (int)(brow >> 10);
        const int rb = (int)(brow & 1023);
        unsigned short* vtb = vt + ((long)b << 20);
#pragma unroll
        for (int m = 0; m < 4; m++) {
            int ntok = rb + wr * 64 + m * 16 + fqp;
#pragma unroll
            for (int n = 0; n < 4; n++) {
                int hd = (int)bcol - 2048 + wc * 64 + n * 16 + fr;
                float bb = bias[2048 + hd];
                uint2 u;
                u.x = cvt_pk_bf16(acc[m][n][0] + bb, acc[m][n][1] + bb);
                u.y = cvt_pk_bf16(acc[m][n][2] + bb, acc[m][n][3] + bb);
                *(uint2*)(vtb + (long)hd * 1024 + ntok) = u;
            }
        }
    }
}

// ---------------------------------------------------------------------------
// Conv-as-GEMM v2: 512 thr (8 waves = 2/SIMD), BK=64, 128B swizzled rows,
// double-buffered. Tile 128 rows x 64 out-ch; wave = 32r x 32c (acc 2x2).
// Grid (32 row-panels, ncol): id%8 = row-panel -> XCD pin. rp: z=rp>>3,
// row=rp&7. Taps read A at row+dk in-LDS. Epilogue: bias+silu, bf16.
// ---------------------------------------------------------------------------
template<int KW, int CI>
__global__ __launch_bounds__(512)
void conv_gemm64(const unsigned short* __restrict__ A, long sAb,
                 const unsigned short* __restrict__ Bw, int CO,
                 const float* __restrict__ bias,
                 unsigned short* __restrict__ C, long sCb, int ldc, int crow_off)
{
    __shared__ __align__(16) unsigned short As[2][144 * 64];
    __shared__ __align__(16) unsigned short Bs[2][KW * 64 * 64];
    const int tid = threadIdx.x, lane = tid & 63, wid = tid >> 6;
    const int wr = wid >> 1, wc = wid & 1;           // 4 x 2 wave grid
    const int rp = blockIdx.x;
    const int z = rp >> 3;
    const long brow = (long)(rp & 7) * 128;
    const long bcol = (long)blockIdx.y * 64;
    const unsigned short* Ab = A + z * sAb + brow * CI;
    const int srow = tid >> 3;                        // 0..63
    const int schk8 = ((tid & 7) ^ (srow & 7)) * 8;
    const int lslot = (tid & 7) * 8;

    f32x4 acc[2][2] = {};

    auto STAGE = [&](int buf, int kk) {
#pragma unroll
        for (int i = 0; i < 2; i++)
            gload_lds16(Ab + (long)(i * 64 + srow) * CI + kk + schk8,
                        &As[buf][(i * 64 + srow) * 64 + lslot]);
        if (tid < 128)   // rows 128..143 (taps need <= 131)
            gload_lds16(Ab + (long)(128 + srow) * CI + kk + schk8,
                        &As[buf][(128 + srow) * 64 + lslot]);
#pragma unroll
        for (int dk = 0; dk < KW; dk++)
            gload_lds16(Bw + ((long)(dk * CO) + bcol + srow) * CI + kk + schk8,
                        &Bs[buf][(dk * 64 + srow) * 64 + lslot]);
    };

    STAGE(0, 0);
    const int fr = lane & 15, g = lane >> 4;
    int cur = 0;
    for (int kk = 0; kk < CI; kk += 64) {
        __syncthreads();                 // drains own stage + barrier
        if (kk + 64 < CI) STAGE(cur ^ 1, kk + 64);
        short8 bfr[KW][2][2];
#pragma unroll
        for (int dk = 0; dk < KW; dk++)
#pragma unroll
            for (int n = 0; n < 2; n++) {
                int rb = dk * 64 + wc * 32 + n * 16 + fr;
#pragma unroll
                for (int k2 = 0; k2 < 2; k2++)
                    bfr[dk][n][k2] = *(const short8*)(&Bs[cur][rb * 64 + (((k2 * 4 + g) ^ (rb & 7)) * 8)]);
            }
#pragma unroll
        for (int m = 0; m < 2; m++) {
#pragma unroll
            for (int dk = 0; dk < KW; dk++) {
                int ra = wr * 32 + m * 16 + fr + dk;
                short8 a0 = *(const short8*)(&As[cur][ra * 64 + ((g ^ (ra & 7)) * 8)]);
                short8 a1 = *(const short8*)(&As[cur][ra * 64 + (((4 + g) ^ (ra & 7)) * 8)]);
#pragma unroll
                for (int n = 0; n < 2; n++) {
                    acc[m][n] = __builtin_amdgcn_mfma_f32_16x16x32_bf16(a0, bfr[dk][n][0], acc[m][n], 0, 0, 0);
                    acc[m][n] = __builtin_amdgcn_mfma_f32_16x16x32_bf16(a1, bfr[dk][n][1], acc[m][n], 0, 0, 0);
                }
            }
        }
        cur ^= 1;
    }

    const int fq = g * 4;
#pragma unroll
    for (int m = 0; m < 2; m++) {
#pragma unroll
        for (int n = 0; n < 2; n++) {
#pragma unroll
            for (int j = 0; j < 4; j++) {
                long row = brow + wr * 32 + m * 16 + fq + j;
                int col = (int)bcol + wc * 32 + n * 16 + fr;
                float v = acc[m][n][j] + bias[col];
                v = v / (1.f + __expf(-v));    // silu
                C[z * sCb + (crow_off + row) * ldc + col] = f2b(v);
            }
        }
    }
}

// ---------------------------------------------------------------------------
// Fused out-proj + gate GEMMs v2: 512 thr (8 waves = 2/SIMD), BK=64,
// swizzled 128B rows, double-buffered (128 KiB). Wave = 32r x 64c per GEMM
// (acc 2x4 each). Grid (32 rows, 8 cols): id%8 = row-panel -> XCD pin.
// Epilogue: X += sigmoid(G)*Y (LAST: write OUT).
// ---------------------------------------------------------------------------
template<int LAST>
__global__ __launch_bounds__(512)
void fused_og(const unsigned short* __restrict__ A1, const unsigned short* __restrict__ B1,
              const float* __restrict__ b1,
              const unsigned short* __restrict__ A2, const unsigned short* __restrict__ B2,
              const float* __restrict__ b2,
              float* __restrict__ X, float* __restrict__ OUT)
{
    __shared__ __align__(16) unsigned short S[2][4][128 * 64];
    const int tid = threadIdx.x, lane = tid & 63, wid = tid >> 6;
    const int wr = wid >> 1, wc = wid & 1;           // 4 x 2 wave grid
    const long brow = (long)blockIdx.x * 128;        // row-major grid
    const long bcol = (long)blockIdx.y * 128;
    const int srow = tid >> 3;                        // 0..63
    const int schk8 = ((tid & 7) ^ (srow & 7)) * 8;
    const int lslot = (tid & 7) * 8;

    const unsigned short* g0 = A1 + (brow + srow) * 1024 + schk8;
    const unsigned short* g1 = B1 + (bcol + srow) * 1024 + schk8;
    const unsigned short* g2 = A2 + (brow + srow) * 1024 + schk8;
    const unsigned short* g3 = B2 + (bcol + srow) * 1024 + schk8;

    f32x4 acc1[2][4] = {}, acc2[2][4] = {};

    auto STAGE = [&](int buf, int kk) {
#pragma unroll
        for (int i = 0; i < 2; i++) {
            int ld = (i * 64 + srow) * 64 + lslot;
            long go = (long)i * 64 * 1024 + kk;
            gload_lds16(g0 + go, &S[buf][0][ld]);
            gload_lds16(g1 + go, &S[buf][1][ld]);
            gload_lds16(g2 + go, &S[buf][2][ld]);
            gload_lds16(g3 + go, &S[buf][3][ld]);
        }
    };

    STAGE(0, 0);
    const int fr = lane & 15, g = lane >> 4;
    int cur = 0;
    for (int kk = 0; kk < 1024; kk += 64) {
        __syncthreads();
        if (kk + 64 < 1024) STAGE(cur ^ 1, kk + 64);
        short8 a1f[2][2], a2f[2][2], b1f[4][2], b2f[4][2];
#pragma unroll
        for (int m = 0; m < 2; m++) {
            int r = wr * 32 + m * 16 + fr;
#pragma unroll
            for (int k2 = 0; k2 < 2; k2++) {
                int sl = r * 64 + (((k2 * 4 + g) ^ (r & 7)) * 8);
                a1f[m][k2] = *(const short8*)(&S[cur][0][sl]);
                a2f[m][k2] = *(const short8*)(&S[cur][2][sl]);
            }
        }
#pragma unroll
        for (int n = 0; n < 4; n++) {
            int r = wc * 64 + n * 16 + fr;
#pragma unroll
            for (int k2 = 0; k2 < 2; k2++) {
                int sl = r * 64 + (((k2 * 4 + g) ^ (r & 7)) * 8);
                b1f[n][k2] = *(const short8*)(&S[cur][1][sl]);
                b2f[n][k2] = *(const short8*)(&S[cur][3][sl]);
            }
        }
#pragma unroll
        for (int m = 0; m < 2; m++)
#pragma unroll
            for (int n = 0; n < 4; n++) {
                acc1[m][n] = __builtin_amdgcn_mfma_f32_16x16x32_bf16(a1f[m][0], b1f[n][0], acc1[m][n], 0, 0, 0);
                acc1[m][n] = __builtin_amdgcn_mfma_f32_16x16x32_bf16(a1f[m][1], b1f[n][1], acc1[m][n], 0, 0, 0);
                acc2[m][n] = __builtin_amdgcn_mfma_f32_16x16x32_bf16(a2f[m][0], b2f[n][0], acc2[m][n], 0, 0, 0);
                acc2[m][n] = __builtin_amdgcn_mfma_f32_16x16x32_bf16(a2f[m][1], b2f[n][1], acc2[m][n], 0, 0, 0);
            }
        cur ^= 1;
    }

    const int fq = g * 4;
#pragma unroll
    for (int m = 0; m < 2; m++) {
#pragma unroll
        for (int n = 0; n < 4; n++) {
#pragma unroll
            for (int j = 0; j < 4; j++) {
                long row = brow + wr * 32 + m * 16 + fq + j;
                int col = (int)bcol + wc * 64 + n * 16 + fr;
                float v1 = acc1[m][n][j] + b1[col];
                float v2 = acc2[m][n][j] + b2[col];
                long idx = row * 1024 + col;
                float r = X[idx] + v1 / (1.f + __expf(-v2));
                if (LAST) OUT[idx] = r; else X[idx] = r;
            }
        }
    }
}

// ---------------------------------------------------------------------------
// Flash attention v5 (unchanged from round 8): KVBLK=64, swapped-QK^T 32x32,
// transposed PV, exp2-domain softmax, LDS dbuf with pre-swizzled source.
// ---------------------------------------------------------------------------
__global__ __launch_bounds__(256)
void attn_kernel(const unsigned short* __restrict__ qkv,
                 const unsigned short* __restrict__ vt,   // VTP (key-permuted)
                 const float* __restrict__ plog,
                 unsigned short* __restrict__ y)
{
    __shared__ __align__(16) unsigned short Kb[2][64 * 64];
    __shared__ __align__(16) unsigned short Vb[2][64 * 64];
    __shared__ float pl[1024];

    const int bh = blockIdx.x;
    const int qt = blockIdx.y;
    const int b = bh >> 4, h = bh & 15;
    const int tid = threadIdx.x, lane = tid & 63, wid = tid >> 6;
    const int c = lane & 31;
    const int hh = lane >> 5;

    const long nb = (long)b * 1024;
    const unsigned short* qbase = qkv + nb * 3072 + h * 64;
    const unsigned short* kbase = qbase + 1024;
    const unsigned short* vtb = vt + (long)bh * 65536;

    for (int i = tid; i < 1024; i += 256) pl[i] = plog[b * 1024 + i] * 1.4426950408889634f;

    const int srow = tid >> 3;                       // 0..31
    const int schk = (tid & 7) ^ (srow & 7);
    const unsigned short* gk = kbase + (long)srow * 3072 + schk * 8;
    const unsigned short* gv = vtb + (long)srow * 1024 + schk * 8;

    auto STAGE = [&](int buf, int kt) {
#pragma unroll
        for (int i = 0; i < 2; i++) {
            gload_lds16(gk + (long)(kt + i * 32) * 3072, &Kb[buf][i * 2048 + tid * 8]);
            gload_lds16(gv + (long)i * 32 * 1024 + kt, &Vb[buf][i * 2048 + tid * 8]);
        }
    };

    const int q0 = qt * 128 + wid * 32;
    short8 qf[4];
#pragma unroll
    for (int d = 0; d < 4; d++)
        qf[d] = *(const short8*)(qbase + (long)(q0 + c) * 3072 + d * 16 + hh * 8);

    float m_run = -1e30f, l_run = 0.f;
    f32x16 o0 = {}, o1 = {};
    const int csw = c & 7;

    STAGE(0, 0);
    int cur = 0;
    for (int kt = 0; kt < 1024; kt += 64) {
        __syncthreads();
        if (kt + 64 < 1024) STAGE(cur ^ 1, kt + 64);

#pragma unroll
        for (int sb = 0; sb < 2; sb++) {
            short8 kf[4];
#pragma unroll
            for (int d = 0; d < 4; d++)
                kf[d] = *(const short8*)(&Kb[cur][(sb * 32 + c) * 64 + (((2 * d + hh) ^ csw) * 8)]);

            f32x16 s = {};
#pragma unroll
            for (int d = 0; d < 4; d++)
                s = __builtin_amdgcn_mfma_f32_32x32x16_bf16(kf[d], qf[d], s, 0, 0, 0);

            float mx = -1e30f;
#pragma unroll
            for (int r = 0; r < 16; r++) {
                int key = (r & 3) + 8 * (r >> 2) + 4 * hh;
                float pv = s[r] + pl[kt + sb * 32 + key];
                s[r] = pv;
                mx = fmaxf(mx, pv);
            }
            mx = fmaxf(mx, __shfl_xor(mx, 32));

            if (!__all(mx - m_run <= 11.5f)) {     // defer-max (T13)
                float mnew = fmaxf(m_run, mx);
                float f = __builtin_amdgcn_exp2f(m_run - mnew);
                l_run *= f;
#pragma unroll
                for (int r = 0; r < 16; r++) { o0[r] *= f; o1[r] *= f; }
                m_run = mnew;
            }

            float sum = 0.f;
#pragma unroll
            for (int r = 0; r < 16; r++) {
                s[r] = __builtin_amdgcn_exp2f(s[r] - m_run);
                sum += s[r];
            }
            sum += __shfl_xor(sum, 32);
            l_run += sum;

            union U8 { unsigned int u[4]; short8 v; } P1, P2;
#pragma unroll
            for (int t = 0; t < 4; t++) {
                P1.u[t] = cvt_pk_bf16(s[2 * t], s[2 * t + 1]);
                P2.u[t] = cvt_pk_bf16(s[8 + 2 * t], s[9 + 2 * t]);
            }

            short8 va00 = *(const short8*)(&Vb[cur][c * 64 + (((sb * 4 + hh) ^ csw) * 8)]);
            short8 va01 = *(const short8*)(&Vb[cur][c * 64 + (((sb * 4 + 2 + hh) ^ csw) * 8)]);
            short8 va10 = *(const short8*)(&Vb[cur][(c + 32) * 64 + (((sb * 4 + hh) ^ csw) * 8)]);
            short8 va11 = *(const short8*)(&Vb[cur][(c + 32) * 64 + (((sb * 4 + 2 + hh) ^ csw) * 8)]);

            o0 = __builtin_amdgcn_mfma_f32_32x32x16_bf16(va00, P1.v, o0, 0, 0, 0);
            o0 = __builtin_amdgcn_mfma_f32_32x32x16_bf16(va01, P2.v, o0, 0, 0, 0);
            o1 = __builtin_amdgcn_mfma_f32_32x32x16_bf16(va10, P1.v, o1, 0, 0, 0);
            o1 = __builtin_amdgcn_mfma_f32_32x32x16_bf16(va11, P2.v, o1, 0, 0, 0);
        }
        cur ^= 1;
    }

    float inv = 1.f / l_run;
    unsigned short* yr = y + (nb + q0 + c) * 1024 + h * 64;
#pragma unroll
    for (int a = 0; a < 4; a++) {
        int d0 = 8 * a + 4 * hh;
        *(unsigned int*)(yr + d0)      = cvt_pk_bf16(o0[4 * a] * inv, o0[4 * a + 1] * inv);
        *(unsigned int*)(yr + d0 + 2)  = cvt_pk_bf16(o0[4 * a + 2] * inv, o0[4 * a + 3] * inv);
        *(unsigned int*)(yr + 32 + d0)     = cvt_pk_bf16(o1[4 * a] * inv, o1[4 * a + 1] * inv);
        *(unsigned int*)(yr + 32 + d0 + 2) = cvt_pk_bf16(o1[4 * a + 2] * inv, o1[4 * a + 3] * inv);
    }
}

// --------------------------------------------------------------------------
__global__ __launch_bounds__(256)
void zcrms_kernel(const float* __restrict__ x, const float* __restrict__ g,
                  unsigned short* __restrict__ hn)
{
    __shared__ float red[8];
    const long row = blockIdx.x;
    const int tid = threadIdx.x;
    const float* xr = x + row * 1024;
    float4 v = *(const float4*)(xr + tid * 4);
    float s = v.x + v.y + v.z + v.w;
#pragma unroll
    for (int m = 32; m; m >>= 1) s += __shfl_xor(s, m);
    const int lane = tid & 63, wid = tid >> 6;
    if (lane == 0) red[wid] = s;
    __syncthreads();
    float mean = (red[0] + red[1] + red[2] + red[3]) * (1.f / 1024.f);
    float c0 = v.x - mean, c1 = v.y - mean, c2 = v.z - mean, c3 = v.w - mean;
    float s2 = c0 * c0 + c1 * c1 + c2 * c2 + c3 * c3;
#pragma unroll
    for (int m = 32; m; m >>= 1) s2 += __shfl_xor(s2, m);
    if (lane == 0) red[4 + wid] = s2;
    __syncthreads();
    float rinv = rsqrtf((red[4] + red[5] + red[6] + red[7]) * (1.f / 1024.f) + 1e-8f);
    const float* gr = g + tid * 4;
    unsigned int lo = (unsigned int)f2b(c0 * rinv * gr[0]) | ((unsigned int)f2b(c1 * rinv * gr[1]) << 16);
    unsigned int hi = (unsigned int)f2b(c2 * rinv * gr[2]) | ((unsigned int)f2b(c3 * rinv * gr[3]) << 16);
    uint2 u; u.x = lo; u.y = hi;
    *(uint2*)(hn + row * 1024 + tid * 4) = u;
}

__global__ __launch_bounds__(1024)
void embed_kernel(const float* __restrict__ patches, const float* __restrict__ W,
                  const float* __restrict__ bias, float* __restrict__ x,
                  unsigned short* __restrict__ xpad)
{
    __shared__ float sp[8][75];
    const long r0 = (long)blockIdx.x * 8;
    const int tid = threadIdx.x;
    for (int i = tid; i < 600; i += 1024) sp[i / 75][i % 75] = patches[r0 * 75 + i];
    __syncthreads();
    float acc[8];
    float bb = bias[tid];
#pragma unroll
    for (int j = 0; j < 8; j++) acc[j] = bb;
    for (int p = 0; p < 75; p++) {
        float w = W[p * 1024 + tid];
#pragma unroll
        for (int j = 0; j < 8; j++) acc[j] += sp[j][p] * w;
    }
#pragma unroll
    for (int j = 0; j < 8; j++) {
        long r = r0 + j;
        x[r * 1024 + tid] = acc[j];
        long bb2 = r >> 10, n = r & 1023;
        xpad[(bb2 * 1028 + n + 2) * 1024 + tid] = f2b(acc[j]);
    }
}

__global__ void rope_table_kernel(float* __restrict__ tab)
{
    int idx = blockIdx.x * 256 + threadIdx.x;   // 32768
    int n = idx >> 5, i = idx & 31;
    float inv = powf(10000.0f, -(float)i * (1.0f / 32.0f));
    float ang = (float)n * inv;
    tab[idx] = cosf(ang);
    tab[32768 + idx] = sinf(ang);
}

__global__ __launch_bounds__(256)
void conv3_kernel(const unsigned short* __restrict__ h2, const float* __restrict__ w3,
                  const float* __restrict__ b3, float* __restrict__ logits)
{
    const long row = (long)blockIdx.x * 4 + (threadIdx.x >> 6);
    const int lane = threadIdx.x & 63;
    const unsigned short* hr = h2 + row * 256;
    float s = 0.f;
#pragma unroll
    for (int t = 0; t < 4; t++) s += b2f(hr[lane + t * 64]) * w3[lane + t * 64];
#pragma unroll
    for (int m = 32; m; m >>= 1) s += __shfl_xor(s, m);
    if (lane == 0) logits[row] = s + b3[0];
}

__global__ __launch_bounds__(256)
void winmax_kernel(const float* __restrict__ logits, float* __restrict__ win)
{
    __shared__ float red[4];
    const int b = blockIdx.x, tid = threadIdx.x;
    float m = -1e30f;
    for (int i = tid; i < 1024; i += 256) m = fmaxf(m, logits[b * 1024 + i]);
#pragma unroll
    for (int k = 32; k; k >>= 1) m = fmaxf(m, __shfl_xor(m, k));
    if ((tid & 63) == 0) red[tid >> 6] = m;
    __syncthreads();
    if (tid == 0) win[b] = fmaxf(fmaxf(red[0], red[1]), fmaxf(red[2], red[3]));
}

// f32 (K,Nc) -> bf16 (Nc,K), batched over z
__global__ __launch_bounds__(256)
void wtrans_kernel(const float* __restrict__ in, unsigned short* __restrict__ out,
                   int K, int Nc)
{
    __shared__ float tile[32][33];
    const long base = (long)blockIdx.z * K * Nc;
    const int k0 = blockIdx.y * 32, n0 = blockIdx.x * 32;
    const int tx = threadIdx.x & 31, ty = threadIdx.x >> 5;
#pragma unroll
    for (int r = ty; r < 32; r += 8) tile[r][tx] = in[base + (long)(k0 + r) * Nc + n0 + tx];
    __syncthreads();
#pragma unroll
    for (int r = ty; r < 32; r += 8) out[base + (long)(n0 + r) * K + k0 + tx] = f2b(tile[tx][r]);
}

// (Co,Ci,Kw) f32 -> [dk][co][ci] bf16
__global__ void wconv_tap_kernel(const float* __restrict__ in, unsigned short* __restrict__ out,
                                 int CI, int KW, int CO, long total)
{
    long idx = (long)blockIdx.x * 256 + threadIdx.x;
    if (idx >= total) return;
    int ci = (int)(idx % CI);
    long t = idx / CI;
    int co = (int)(t % CO);
    int dk = (int)(t / CO);
    out[idx] = f2b(in[((long)co * CI + ci) * KW + dk]);
}

// ---------------------------------------------------------------------------
extern "C" void kernel_launch(void* const* d_in, const int* in_sizes, int n_in,
                              void* d_out, int out_size, void* d_ws, size_t ws_size,
                              hipStream_t stream)
{
    (void)in_sizes; (void)n_in; (void)out_size; (void)ws_size;
    const float* patches = (const float*)d_in[0];
    const float* embed_w = (const float*)d_in[1];
    const float* embed_b = (const float*)d_in[2];
    const float* bd_w1 = (const float*)d_in[3];
    const float* bd_b1 = (const float*)d_in[4];
    const float* bd_w2 = (const float*)d_in[5];
    const float* bd_b2 = (const float*)d_in[6];
    const float* bd_w3 = (const float*)d_in[7];
    const float* bd_b3 = (const float*)d_in[8];
    const float* norm_g = (const float*)d_in[9];
    const float* qkv_w = (const float*)d_in[10];
    const float* qkv_b = (const float*)d_in[11];
    const float* out_w = (const float*)d_in[12];
    const float* out_b = (const float*)d_in[13];
    const float* gate_w = (const float*)d_in[14];
    const float* gate_b = (const float*)d_in[15];

    char* p = (char*)d_ws;
    auto alloc = [&](size_t bytes) { char* r = p; p += (bytes + 255) & ~(size_t)255; return r; };
    unsigned short* WQ   = (unsigned short*)alloc(3ll * 3072 * 1024 * 2);
    unsigned short* WO   = (unsigned short*)alloc(3ll * 1024 * 1024 * 2);
    unsigned short* WG   = (unsigned short*)alloc(3ll * 1024 * 1024 * 2);
    unsigned short* W1S  = (unsigned short*)alloc(5ll * 512 * 1024 * 2);
    unsigned short* W2S  = (unsigned short*)alloc(3ll * 256 * 512 * 2);
    unsigned short* XPAD = (unsigned short*)alloc(4ll * 1028 * 1024 * 2);
    unsigned short* H1P  = (unsigned short*)alloc(4ll * 1026 * 512 * 2);
    unsigned short* H2   = (unsigned short*)alloc(4ll * 1024 * 256 * 2);
    float*          X    = (float*)alloc(4ll * 1024 * 1024 * 4);
    unsigned short* HN   = (unsigned short*)alloc(4096ll * 1024 * 2);
    unsigned short* QKV  = (unsigned short*)alloc(4096ll * 3072 * 2);
    unsigned short* YATT = (unsigned short*)alloc(4096ll * 1024 * 2);
    float*          LOGI = (float*)alloc(4096 * 4);
    float*          ROPE = (float*)alloc(65536 * 4);
    // VTP (B,H,64,1024) bf16 = 8MB aliased onto XPAD (conv pipeline done first)
    unsigned short* VT   = XPAD;

    hipMemsetAsync(XPAD, 0, 4ll * 1028 * 1024 * 2, stream);
    hipMemsetAsync(H1P, 0, 4ll * 1026 * 512 * 2, stream);

    wtrans_kernel<<<dim3(96, 32, 3), 256, 0, stream>>>(qkv_w, WQ, 1024, 3072);
    wtrans_kernel<<<dim3(32, 32, 3), 256, 0, stream>>>(out_w, WO, 1024, 1024);
    wtrans_kernel<<<dim3(32, 32, 3), 256, 0, stream>>>(gate_w, WG, 1024, 1024);
    wconv_tap_kernel<<<10240, 256, 0, stream>>>(bd_w1, W1S, 1024, 5, 512, 5ll * 512 * 1024);
    wconv_tap_kernel<<<1536, 256, 0, stream>>>(bd_w2, W2S, 512, 3, 256, 3ll * 256 * 512);
    rope_table_kernel<<<128, 256, 0, stream>>>(ROPE);
    embed_kernel<<<512, 1024, 0, stream>>>(patches, embed_w, embed_b, X, XPAD);

    conv_gemm64<5, 1024><<<dim3(32, 8), 512, 0, stream>>>(XPAD, 1028ll * 1024, W1S, 512, bd_b1,
                                                          H1P, 1026ll * 512, 512, 1);
    conv_gemm64<3, 512><<<dim3(32, 4), 512, 0, stream>>>(H1P, 1026ll * 512, W2S, 256, bd_b2,
                                                         H2, 1024ll * 256, 256, 0);
    conv3_kernel<<<1024, 256, 0, stream>>>(H2, bd_w3, bd_b3, LOGI);
    winmax_kernel<<<4, 256, 0, stream>>>(LOGI, (float*)d_out + 4194304);

    for (int l = 0; l < 3; l++) {
        zcrms_kernel<<<4096, 256, 0, stream>>>(X, norm_g + l * 1024, HN);
        qkv_gemm<<<dim3(32, 24), 256, 0, stream>>>(HN, WQ + (long)l * 3072 * 1024,
                                                   qkv_b + l * 3072, QKV, VT, ROPE);
        attn_kernel<<<dim3(64, 8), 256, 0, stream>>>(QKV, VT, LOGI, YATT);
        if (l < 2)
            fused_og<0><<<dim3(32, 8), 512, 0, stream>>>(YATT, WO + (long)l * 1024 * 1024, out_b + l * 1024,
                                                         HN, WG + (long)l * 1024 * 1024, gate_b + l * 1024,
                                                         X, nullptr);
        else
            fused_og<1><<<dim3(32, 8), 512, 0, stream>>>(YATT, WO + (long)l * 1024 * 1024, out_b + l * 1024,
                                                         HN, WG + (long)l * 1024 * 1024, gate_b + l * 1024,
                                                         X, (float*)d_out);
    }
}

// Round 10
// 428.327 us; speedup vs baseline: 1.3532x; 1.0369x over previous
//
#include <hip/hip_runtime.h>
#include <stdint.h>
#include <math.h>

typedef __attribute__((ext_vector_type(8))) short short8;
typedef __attribute__((ext_vector_type(4))) float f32x4;
typedef __attribute__((ext_vector_type(16))) float f32x16;

__device__ __forceinline__ float b2f(unsigned short u) {
    union { unsigned int i; float f; } v; v.i = ((unsigned int)u) << 16; return v.f;
}
__device__ __forceinline__ unsigned short f2b(float f) {
    union { float f; unsigned int i; } v; v.f = f;
    unsigned int r = v.i + 0x7fffu + ((v.i >> 16) & 1u);
    return (unsigned short)(r >> 16);
}
__device__ __forceinline__ unsigned int cvt_pk_bf16(float lo, float hi) {
    unsigned int r;
    asm("v_cvt_pk_bf16_f32 %0, %1, %2" : "=v"(r) : "v"(lo), "v"(hi));
    return r;
}

__device__ __forceinline__ void gload_lds16(const void* g, void* l) {
    __builtin_amdgcn_global_load_lds((__attribute__((address_space(1))) void*)g,
                                     (__attribute__((address_space(3))) void*)l,
                                     16, 0, 0);
}

// ---------------------------------------------------------------------------
// qkv GEMM v3: 128x128, BK=64, source-swizzled, NOW double-buffered with the
// proven 2-phase schedule (single barrier/iter; STAGE(t+1) hides under
// tile t's ds_reads + 32 MFMAs). 64 KiB LDS -> 2 blocks/CU.
// Fused RoPE epilogue + fused V->VT store. Grid (32 rows, 24 cols): XCD pin.
// ---------------------------------------------------------------------------
__global__ __launch_bounds__(256, 2)
void qkv_gemm(const unsigned short* __restrict__ A,
              const unsigned short* __restrict__ Bw,
              const float* __restrict__ bias,
              unsigned short* __restrict__ Cb,
              unsigned short* __restrict__ vt,
              const float* __restrict__ rope)
{
    __shared__ __align__(16) unsigned short As[2][128 * 64];
    __shared__ __align__(16) unsigned short Bs[2][128 * 64];
    const int tid = threadIdx.x;
    const int lane = tid & 63, wid = tid >> 6;
    const int wr = wid >> 1, wc = wid & 1;
    const long brow = (long)blockIdx.x * 128;   // row-major grid (XCD pin)
    const long bcol = (long)blockIdx.y * 128;

    const int srow = tid >> 3;                       // 0..31
    const int schk = (tid & 7) ^ (srow & 7);
    const unsigned short* gA = A + (brow + srow) * 1024 + schk * 8;
    const unsigned short* gB = Bw + (bcol + srow) * 1024 + schk * 8;

    auto STAGE = [&](int buf, int kk) {
#pragma unroll
        for (int i = 0; i < 4; i++) {
            gload_lds16(gA + (long)i * 32 * 1024 + kk, &As[buf][i * 2048 + tid * 8]);
            gload_lds16(gB + (long)i * 32 * 1024 + kk, &Bs[buf][i * 2048 + tid * 8]);
        }
    };

    f32x4 acc[4][4] = {};
    const int fr = lane & 15, g = lane >> 4;
    const int fsw = fr & 7;

    STAGE(0, 0);
    int cur = 0;
    for (int kk = 0; kk < 1024; kk += 64) {
        __syncthreads();                 // drains prev stage (vmcnt 0) + barrier
        if (kk + 64 < 1024) STAGE(cur ^ 1, kk + 64);
        short8 af[4][2], bf[4][2];
#pragma unroll
        for (int m = 0; m < 4; m++) {
            int r = wr * 64 + m * 16 + fr;
#pragma unroll
            for (int k2 = 0; k2 < 2; k2++)
                af[m][k2] = *(const short8*)(&As[cur][r * 64 + (((k2 * 4 + g) ^ fsw) * 8)]);
        }
#pragma unroll
        for (int n = 0; n < 4; n++) {
            int r = wc * 64 + n * 16 + fr;
#pragma unroll
            for (int k2 = 0; k2 < 2; k2++)
                bf[n][k2] = *(const short8*)(&Bs[cur][r * 64 + (((k2 * 4 + g) ^ fsw) * 8)]);
        }
#pragma unroll
        for (int m = 0; m < 4; m++)
#pragma unroll
            for (int n = 0; n < 4; n++) {
                acc[m][n] = __builtin_amdgcn_mfma_f32_16x16x32_bf16(af[m][0], bf[n][0], acc[m][n], 0, 0, 0);
                acc[m][n] = __builtin_amdgcn_mfma_f32_16x16x32_bf16(af[m][1], bf[n][1], acc[m][n], 0, 0, 0);
            }
        cur ^= 1;
    }

    const int fq = g * 4;
    if (bcol < 2048) {
#pragma unroll
        for (int m = 0; m < 4; m++) {
#pragma unroll
            for (int n = 0; n < 4; n++) {
#pragma unroll
                for (int j = 0; j < 4; j++) {
                    long row = brow + wr * 64 + m * 16 + fq + j;
                    int col = (int)bcol + wc * 64 + n * 16 + fr;
                    float v = acc[m][n][j] + bias[col];
                    float part = __shfl_xor(v, 1);
                    int d = col & 63;
                    int i2 = d >> 1;
                    int ntok = (int)(row & 1023);
                    float cc = rope[ntok * 32 + i2];
                    float ss = rope[32768 + ntok * 32 + i2];
                    v = (d & 1) ? (part * ss + v * cc) : (v * cc - part * ss);
                    if (col < 1024) v *= 0.18033688011112042f;   // 0.125*log2(e)
                    Cb[row * 3072 + col] = f2b(v);
                }
            }
        }
    } else {
        const int fqp = (fq == 4) ? 8 : (fq == 8) ? 4 : fq;
        const int b = (int)(brow >> 10);
        const int rb = (int)(brow & 1023);
        unsigned short* vtb = vt + ((long)b << 20);
#pragma unroll
        for (int m = 0; m < 4; m++) {
            int ntok = rb + wr * 64 + m * 16 + fqp;
#pragma unroll
            for (int n = 0; n < 4; n++) {
                int hd = (int)bcol - 2048 + wc * 64 + n * 16 + fr;
                float bb = bias[2048 + hd];
                uint2 u;
                u.x = cvt_pk_bf16(acc[m][n][0] + bb, acc[m][n][1] + bb);
                u.y = cvt_pk_bf16(acc[m][n][2] + bb, acc[m][n][3] + bb);
                *(uint2*)(vtb + (long)hd * 1024 + ntok) = u;
            }
        }
    }
}

// ---------------------------------------------------------------------------
// Conv-as-GEMM v2 (unchanged from round 9).
// ---------------------------------------------------------------------------
template<int KW, int CI>
__global__ __launch_bounds__(512)
void conv_gemm64(const unsigned short* __restrict__ A, long sAb,
                 const unsigned short* __restrict__ Bw, int CO,
                 const float* __restrict__ bias,
                 unsigned short* __restrict__ C, long sCb, int ldc, int crow_off)
{
    __shared__ __align__(16) unsigned short As[2][144 * 64];
    __shared__ __align__(16) unsigned short Bs[2][KW * 64 * 64];
    const int tid = threadIdx.x, lane = tid & 63, wid = tid >> 6;
    const int wr = wid >> 1, wc = wid & 1;           // 4 x 2 wave grid
    const int rp = blockIdx.x;
    const int z = rp >> 3;
    const long brow = (long)(rp & 7) * 128;
    const long bcol = (long)blockIdx.y * 64;
    const unsigned short* Ab = A + z * sAb + brow * CI;
    const int srow = tid >> 3;                        // 0..63
    const int schk8 = ((tid & 7) ^ (srow & 7)) * 8;
    const int lslot = (tid & 7) * 8;

    f32x4 acc[2][2] = {};

    auto STAGE = [&](int buf, int kk) {
#pragma unroll
        for (int i = 0; i < 2; i++)
            gload_lds16(Ab + (long)(i * 64 + srow) * CI + kk + schk8,
                        &As[buf][(i * 64 + srow) * 64 + lslot]);
        if (tid < 128)
            gload_lds16(Ab + (long)(128 + srow) * CI + kk + schk8,
                        &As[buf][(128 + srow) * 64 + lslot]);
#pragma unroll
        for (int dk = 0; dk < KW; dk++)
            gload_lds16(Bw + ((long)(dk * CO) + bcol + srow) * CI + kk + schk8,
                        &Bs[buf][(dk * 64 + srow) * 64 + lslot]);
    };

    STAGE(0, 0);
    const int fr = lane & 15, g = lane >> 4;
    int cur = 0;
    for (int kk = 0; kk < CI; kk += 64) {
        __syncthreads();
        if (kk + 64 < CI) STAGE(cur ^ 1, kk + 64);
        short8 bfr[KW][2][2];
#pragma unroll
        for (int dk = 0; dk < KW; dk++)
#pragma unroll
            for (int n = 0; n < 2; n++) {
                int rb = dk * 64 + wc * 32 + n * 16 + fr;
#pragma unroll
                for (int k2 = 0; k2 < 2; k2++)
                    bfr[dk][n][k2] = *(const short8*)(&Bs[cur][rb * 64 + (((k2 * 4 + g) ^ (rb & 7)) * 8)]);
            }
#pragma unroll
        for (int m = 0; m < 2; m++) {
#pragma unroll
            for (int dk = 0; dk < KW; dk++) {
                int ra = wr * 32 + m * 16 + fr + dk;
                short8 a0 = *(const short8*)(&As[cur][ra * 64 + ((g ^ (ra & 7)) * 8)]);
                short8 a1 = *(const short8*)(&As[cur][ra * 64 + (((4 + g) ^ (ra & 7)) * 8)]);
#pragma unroll
                for (int n = 0; n < 2; n++) {
                    acc[m][n] = __builtin_amdgcn_mfma_f32_16x16x32_bf16(a0, bfr[dk][n][0], acc[m][n], 0, 0, 0);
                    acc[m][n] = __builtin_amdgcn_mfma_f32_16x16x32_bf16(a1, bfr[dk][n][1], acc[m][n], 0, 0, 0);
                }
            }
        }
        cur ^= 1;
    }

    const int fq = g * 4;
#pragma unroll
    for (int m = 0; m < 2; m++) {
#pragma unroll
        for (int n = 0; n < 2; n++) {
#pragma unroll
            for (int j = 0; j < 4; j++) {
                long row = brow + wr * 32 + m * 16 + fq + j;
                int col = (int)bcol + wc * 32 + n * 16 + fr;
                float v = acc[m][n][j] + bias[col];
                v = v / (1.f + __expf(-v));    // silu
                C[z * sCb + (crow_off + row) * ldc + col] = f2b(v);
            }
        }
    }
}

// ---------------------------------------------------------------------------
// Fused out-proj + gate GEMMs v2 (unchanged from round 9).
// ---------------------------------------------------------------------------
template<int LAST>
__global__ __launch_bounds__(512)
void fused_og(const unsigned short* __restrict__ A1, const unsigned short* __restrict__ B1,
              const float* __restrict__ b1,
              const unsigned short* __restrict__ A2, const unsigned short* __restrict__ B2,
              const float* __restrict__ b2,
              float* __restrict__ X, float* __restrict__ OUT)
{
    __shared__ __align__(16) unsigned short S[2][4][128 * 64];
    const int tid = threadIdx.x, lane = tid & 63, wid = tid >> 6;
    const int wr = wid >> 1, wc = wid & 1;
    const long brow = (long)blockIdx.x * 128;
    const long bcol = (long)blockIdx.y * 128;
    const int srow = tid >> 3;
    const int schk8 = ((tid & 7) ^ (srow & 7)) * 8;
    const int lslot = (tid & 7) * 8;

    const unsigned short* g0 = A1 + (brow + srow) * 1024 + schk8;
    const unsigned short* g1 = B1 + (bcol + srow) * 1024 + schk8;
    const unsigned short* g2 = A2 + (brow + srow) * 1024 + schk8;
    const unsigned short* g3 = B2 + (bcol + srow) * 1024 + schk8;

    f32x4 acc1[2][4] = {}, acc2[2][4] = {};

    auto STAGE = [&](int buf, int kk) {
#pragma unroll
        for (int i = 0; i < 2; i++) {
            int ld = (i * 64 + srow) * 64 + lslot;
            long go = (long)i * 64 * 1024 + kk;
            gload_lds16(g0 + go, &S[buf][0][ld]);
            gload_lds16(g1 + go, &S[buf][1][ld]);
            gload_lds16(g2 + go, &S[buf][2][ld]);
            gload_lds16(g3 + go, &S[buf][3][ld]);
        }
    };

    STAGE(0, 0);
    const int fr = lane & 15, g = lane >> 4;
    int cur = 0;
    for (int kk = 0; kk < 1024; kk += 64) {
        __syncthreads();
        if (kk + 64 < 1024) STAGE(cur ^ 1, kk + 64);
        short8 a1f[2][2], a2f[2][2], b1f[4][2], b2f[4][2];
#pragma unroll
        for (int m = 0; m < 2; m++) {
            int r = wr * 32 + m * 16 + fr;
#pragma unroll
            for (int k2 = 0; k2 < 2; k2++) {
                int sl = r * 64 + (((k2 * 4 + g) ^ (r & 7)) * 8);
                a1f[m][k2] = *(const short8*)(&S[cur][0][sl]);
                a2f[m][k2] = *(const short8*)(&S[cur][2][sl]);
            }
        }
#pragma unroll
        for (int n = 0; n < 4; n++) {
            int r = wc * 64 + n * 16 + fr;
#pragma unroll
            for (int k2 = 0; k2 < 2; k2++) {
                int sl = r * 64 + (((k2 * 4 + g) ^ (r & 7)) * 8);
                b1f[n][k2] = *(const short8*)(&S[cur][1][sl]);
                b2f[n][k2] = *(const short8*)(&S[cur][3][sl]);
            }
        }
#pragma unroll
        for (int m = 0; m < 2; m++)
#pragma unroll
            for (int n = 0; n < 4; n++) {
                acc1[m][n] = __builtin_amdgcn_mfma_f32_16x16x32_bf16(a1f[m][0], b1f[n][0], acc1[m][n], 0, 0, 0);
                acc1[m][n] = __builtin_amdgcn_mfma_f32_16x16x32_bf16(a1f[m][1], b1f[n][1], acc1[m][n], 0, 0, 0);
                acc2[m][n] = __builtin_amdgcn_mfma_f32_16x16x32_bf16(a2f[m][0], b2f[n][0], acc2[m][n], 0, 0, 0);
                acc2[m][n] = __builtin_amdgcn_mfma_f32_16x16x32_bf16(a2f[m][1], b2f[n][1], acc2[m][n], 0, 0, 0);
            }
        cur ^= 1;
    }

    const int fq = g * 4;
#pragma unroll
    for (int m = 0; m < 2; m++) {
#pragma unroll
        for (int n = 0; n < 4; n++) {
#pragma unroll
            for (int j = 0; j < 4; j++) {
                long row = brow + wr * 32 + m * 16 + fq + j;
                int col = (int)bcol + wc * 64 + n * 16 + fr;
                float v1 = acc1[m][n][j] + b1[col];
                float v2 = acc2[m][n][j] + b2[col];
                long idx = row * 1024 + col;
                float r = X[idx] + v1 / (1.f + __expf(-v2));
                if (LAST) OUT[idx] = r; else X[idx] = r;
            }
        }
    }
}

// ---------------------------------------------------------------------------
// Flash attention v5 (unchanged from round 8).
// ---------------------------------------------------------------------------
__global__ __launch_bounds__(256)
void attn_kernel(const unsigned short* __restrict__ qkv,
                 const unsigned short* __restrict__ vt,   // VTP (key-permuted)
                 const float* __restrict__ plog,
                 unsigned short* __restrict__ y)
{
    __shared__ __align__(16) unsigned short Kb[2][64 * 64];
    __shared__ __align__(16) unsigned short Vb[2][64 * 64];
    __shared__ float pl[1024];

    const int bh = blockIdx.x;
    const int qt = blockIdx.y;
    const int b = bh >> 4, h = bh & 15;
    const int tid = threadIdx.x, lane = tid & 63, wid = tid >> 6;
    const int c = lane & 31;
    const int hh = lane >> 5;

    const long nb = (long)b * 1024;
    const unsigned short* qbase = qkv + nb * 3072 + h * 64;
    const unsigned short* kbase = qbase + 1024;
    const unsigned short* vtb = vt + (long)bh * 65536;

    for (int i = tid; i < 1024; i += 256) pl[i] = plog[b * 1024 + i] * 1.4426950408889634f;

    const int srow = tid >> 3;
    const int schk = (tid & 7) ^ (srow & 7);
    const unsigned short* gk = kbase + (long)srow * 3072 + schk * 8;
    const unsigned short* gv = vtb + (long)srow * 1024 + schk * 8;

    auto STAGE = [&](int buf, int kt) {
#pragma unroll
        for (int i = 0; i < 2; i++) {
            gload_lds16(gk + (long)(kt + i * 32) * 3072, &Kb[buf][i * 2048 + tid * 8]);
            gload_lds16(gv + (long)i * 32 * 1024 + kt, &Vb[buf][i * 2048 + tid * 8]);
        }
    };

    const int q0 = qt * 128 + wid * 32;
    short8 qf[4];
#pragma unroll
    for (int d = 0; d < 4; d++)
        qf[d] = *(const short8*)(qbase + (long)(q0 + c) * 3072 + d * 16 + hh * 8);

    float m_run = -1e30f, l_run = 0.f;
    f32x16 o0 = {}, o1 = {};
    const int csw = c & 7;

    STAGE(0, 0);
    int cur = 0;
    for (int kt = 0; kt < 1024; kt += 64) {
        __syncthreads();
        if (kt + 64 < 1024) STAGE(cur ^ 1, kt + 64);

#pragma unroll
        for (int sb = 0; sb < 2; sb++) {
            short8 kf[4];
#pragma unroll
            for (int d = 0; d < 4; d++)
                kf[d] = *(const short8*)(&Kb[cur][(sb * 32 + c) * 64 + (((2 * d + hh) ^ csw) * 8)]);

            f32x16 s = {};
#pragma unroll
            for (int d = 0; d < 4; d++)
                s = __builtin_amdgcn_mfma_f32_32x32x16_bf16(kf[d], qf[d], s, 0, 0, 0);

            float mx = -1e30f;
#pragma unroll
            for (int r = 0; r < 16; r++) {
                int key = (r & 3) + 8 * (r >> 2) + 4 * hh;
                float pv = s[r] + pl[kt + sb * 32 + key];
                s[r] = pv;
                mx = fmaxf(mx, pv);
            }
            mx = fmaxf(mx, __shfl_xor(mx, 32));

            if (!__all(mx - m_run <= 11.5f)) {     // defer-max (T13)
                float mnew = fmaxf(m_run, mx);
                float f = __builtin_amdgcn_exp2f(m_run - mnew);
                l_run *= f;
#pragma unroll
                for (int r = 0; r < 16; r++) { o0[r] *= f; o1[r] *= f; }
                m_run = mnew;
            }

            float sum = 0.f;
#pragma unroll
            for (int r = 0; r < 16; r++) {
                s[r] = __builtin_amdgcn_exp2f(s[r] - m_run);
                sum += s[r];
            }
            sum += __shfl_xor(sum, 32);
            l_run += sum;

            union U8 { unsigned int u[4]; short8 v; } P1, P2;
#pragma unroll
            for (int t = 0; t < 4; t++) {
                P1.u[t] = cvt_pk_bf16(s[2 * t], s[2 * t + 1]);
                P2.u[t] = cvt_pk_bf16(s[8 + 2 * t], s[9 + 2 * t]);
            }

            short8 va00 = *(const short8*)(&Vb[cur][c * 64 + (((sb * 4 + hh) ^ csw) * 8)]);
            short8 va01 = *(const short8*)(&Vb[cur][c * 64 + (((sb * 4 + 2 + hh) ^ csw) * 8)]);
            short8 va10 = *(const short8*)(&Vb[cur][(c + 32) * 64 + (((sb * 4 + hh) ^ csw) * 8)]);
            short8 va11 = *(const short8*)(&Vb[cur][(c + 32) * 64 + (((sb * 4 + 2 + hh) ^ csw) * 8)]);

            o0 = __builtin_amdgcn_mfma_f32_32x32x16_bf16(va00, P1.v, o0, 0, 0, 0);
            o0 = __builtin_amdgcn_mfma_f32_32x32x16_bf16(va01, P2.v, o0, 0, 0, 0);
            o1 = __builtin_amdgcn_mfma_f32_32x32x16_bf16(va10, P1.v, o1, 0, 0, 0);
            o1 = __builtin_amdgcn_mfma_f32_32x32x16_bf16(va11, P2.v, o1, 0, 0, 0);
        }
        cur ^= 1;
    }

    float inv = 1.f / l_run;
    unsigned short* yr = y + (nb + q0 + c) * 1024 + h * 64;
#pragma unroll
    for (int a = 0; a < 4; a++) {
        int d0 = 8 * a + 4 * hh;
        *(unsigned int*)(yr + d0)      = cvt_pk_bf16(o0[4 * a] * inv, o0[4 * a + 1] * inv);
        *(unsigned int*)(yr + d0 + 2)  = cvt_pk_bf16(o0[4 * a + 2] * inv, o0[4 * a + 3] * inv);
        *(unsigned int*)(yr + 32 + d0)     = cvt_pk_bf16(o1[4 * a] * inv, o1[4 * a + 1] * inv);
        *(unsigned int*)(yr + 32 + d0 + 2) = cvt_pk_bf16(o1[4 * a + 2] * inv, o1[4 * a + 3] * inv);
    }
}

// --------------------------------------------------------------------------
__global__ __launch_bounds__(256)
void zcrms_kernel(const float* __restrict__ x, const float* __restrict__ g,
                  unsigned short* __restrict__ hn)
{
    __shared__ float red[8];
    const long row = blockIdx.x;
    const int tid = threadIdx.x;
    const float* xr = x + row * 1024;
    float4 v = *(const float4*)(xr + tid * 4);
    float s = v.x + v.y + v.z + v.w;
#pragma unroll
    for (int m = 32; m; m >>= 1) s += __shfl_xor(s, m);
    const int lane = tid & 63, wid = tid >> 6;
    if (lane == 0) red[wid] = s;
    __syncthreads();
    float mean = (red[0] + red[1] + red[2] + red[3]) * (1.f / 1024.f);
    float c0 = v.x - mean, c1 = v.y - mean, c2 = v.z - mean, c3 = v.w - mean;
    float s2 = c0 * c0 + c1 * c1 + c2 * c2 + c3 * c3;
#pragma unroll
    for (int m = 32; m; m >>= 1) s2 += __shfl_xor(s2, m);
    if (lane == 0) red[4 + wid] = s2;
    __syncthreads();
    float rinv = rsqrtf((red[4] + red[5] + red[6] + red[7]) * (1.f / 1024.f) + 1e-8f);
    const float* gr = g + tid * 4;
    unsigned int lo = (unsigned int)f2b(c0 * rinv * gr[0]) | ((unsigned int)f2b(c1 * rinv * gr[1]) << 16);
    unsigned int hi = (unsigned int)f2b(c2 * rinv * gr[2]) | ((unsigned int)f2b(c3 * rinv * gr[3]) << 16);
    uint2 u; u.x = lo; u.y = hi;
    *(uint2*)(hn + row * 1024 + tid * 4) = u;
}

__global__ __launch_bounds__(1024)
void embed_kernel(const float* __restrict__ patches, const float* __restrict__ W,
                  const float* __restrict__ bias, float* __restrict__ x,
                  unsigned short* __restrict__ xpad)
{
    __shared__ float sp[8][75];
    const long r0 = (long)blockIdx.x * 8;
    const int tid = threadIdx.x;
    for (int i = tid; i < 600; i += 1024) sp[i / 75][i % 75] = patches[r0 * 75 + i];
    __syncthreads();
    float acc[8];
    float bb = bias[tid];
#pragma unroll
    for (int j = 0; j < 8; j++) acc[j] = bb;
    for (int p = 0; p < 75; p++) {
        float w = W[p * 1024 + tid];
#pragma unroll
        for (int j = 0; j < 8; j++) acc[j] += sp[j][p] * w;
    }
#pragma unroll
    for (int j = 0; j < 8; j++) {
        long r = r0 + j;
        x[r * 1024 + tid] = acc[j];
        long bb2 = r >> 10, n = r & 1023;
        xpad[(bb2 * 1028 + n + 2) * 1024 + tid] = f2b(acc[j]);
    }
}

__global__ void rope_table_kernel(float* __restrict__ tab)
{
    int idx = blockIdx.x * 256 + threadIdx.x;   // 32768
    int n = idx >> 5, i = idx & 31;
    float inv = powf(10000.0f, -(float)i * (1.0f / 32.0f));
    float ang = (float)n * inv;
    tab[idx] = cosf(ang);
    tab[32768 + idx] = sinf(ang);
}

__global__ __launch_bounds__(256)
void conv3_kernel(const unsigned short* __restrict__ h2, const float* __restrict__ w3,
                  const float* __restrict__ b3, float* __restrict__ logits)
{
    const long row = (long)blockIdx.x * 4 + (threadIdx.x >> 6);
    const int lane = threadIdx.x & 63;
    const unsigned short* hr = h2 + row * 256;
    float s = 0.f;
#pragma unroll
    for (int t = 0; t < 4; t++) s += b2f(hr[lane + t * 64]) * w3[lane + t * 64];
#pragma unroll
    for (int m = 32; m; m >>= 1) s += __shfl_xor(s, m);
    if (lane == 0) logits[row] = s + b3[0];
}

__global__ __launch_bounds__(256)
void winmax_kernel(const float* __restrict__ logits, float* __restrict__ win)
{
    __shared__ float red[4];
    const int b = blockIdx.x, tid = threadIdx.x;
    float m = -1e30f;
    for (int i = tid; i < 1024; i += 256) m = fmaxf(m, logits[b * 1024 + i]);
#pragma unroll
    for (int k = 32; k; k >>= 1) m = fmaxf(m, __shfl_xor(m, k));
    if ((tid & 63) == 0) red[tid >> 6] = m;
    __syncthreads();
    if (tid == 0) win[b] = fmaxf(fmaxf(red[0], red[1]), fmaxf(red[2], red[3]));
}

// f32 (K,Nc) -> bf16 (Nc,K), batched over z
__global__ __launch_bounds__(256)
void wtrans_kernel(const float* __restrict__ in, unsigned short* __restrict__ out,
                   int K, int Nc)
{
    __shared__ float tile[32][33];
    const long base = (long)blockIdx.z * K * Nc;
    const int k0 = blockIdx.y * 32, n0 = blockIdx.x * 32;
    const int tx = threadIdx.x & 31, ty = threadIdx.x >> 5;
#pragma unroll
    for (int r = ty; r < 32; r += 8) tile[r][tx] = in[base + (long)(k0 + r) * Nc + n0 + tx];
    __syncthreads();
#pragma unroll
    for (int r = ty; r < 32; r += 8) out[base + (long)(n0 + r) * K + k0 + tx] = f2b(tile[tx][r]);
}

// (Co,Ci,Kw) f32 -> [dk][co][ci] bf16
__global__ void wconv_tap_kernel(const float* __restrict__ in, unsigned short* __restrict__ out,
                                 int CI, int KW, int CO, long total)
{
    long idx = (long)blockIdx.x * 256 + threadIdx.x;
    if (idx >= total) return;
    int ci = (int)(idx % CI);
    long t = idx / CI;
    int co = (int)(t % CO);
    int dk = (int)(t / CO);
    out[idx] = f2b(in[((long)co * CI + ci) * KW + dk]);
}

// ---------------------------------------------------------------------------
extern "C" void kernel_launch(void* const* d_in, const int* in_sizes, int n_in,
                              void* d_out, int out_size, void* d_ws, size_t ws_size,
                              hipStream_t stream)
{
    (void)in_sizes; (void)n_in; (void)out_size; (void)ws_size;
    const float* patches = (const float*)d_in[0];
    const float* embed_w = (const float*)d_in[1];
    const float* embed_b = (const float*)d_in[2];
    const float* bd_w1 = (const float*)d_in[3];
    const float* bd_b1 = (const float*)d_in[4];
    const float* bd_w2 = (const float*)d_in[5];
    const float* bd_b2 = (const float*)d_in[6];
    const float* bd_w3 = (const float*)d_in[7];
    const float* bd_b3 = (const float*)d_in[8];
    const float* norm_g = (const float*)d_in[9];
    const float* qkv_w = (const float*)d_in[10];
    const float* qkv_b = (const float*)d_in[11];
    const float* out_w = (const float*)d_in[12];
    const float* out_b = (const float*)d_in[13];
    const float* gate_w = (const float*)d_in[14];
    const float* gate_b = (const float*)d_in[15];

    char* p = (char*)d_ws;
    auto alloc = [&](size_t bytes) { char* r = p; p += (bytes + 255) & ~(size_t)255; return r; };
    unsigned short* WQ   = (unsigned short*)alloc(3ll * 3072 * 1024 * 2);
    unsigned short* WO   = (unsigned short*)alloc(3ll * 1024 * 1024 * 2);
    unsigned short* WG   = (unsigned short*)alloc(3ll * 1024 * 1024 * 2);
    unsigned short* W1S  = (unsigned short*)alloc(5ll * 512 * 1024 * 2);
    unsigned short* W2S  = (unsigned short*)alloc(3ll * 256 * 512 * 2);
    unsigned short* XPAD = (unsigned short*)alloc(4ll * 1028 * 1024 * 2);
    unsigned short* H1P  = (unsigned short*)alloc(4ll * 1026 * 512 * 2);
    unsigned short* H2   = (unsigned short*)alloc(4ll * 1024 * 256 * 2);
    float*          X    = (float*)alloc(4ll * 1024 * 1024 * 4);
    unsigned short* HN   = (unsigned short*)alloc(4096ll * 1024 * 2);
    unsigned short* QKV  = (unsigned short*)alloc(4096ll * 3072 * 2);
    unsigned short* YATT = (unsigned short*)alloc(4096ll * 1024 * 2);
    float*          LOGI = (float*)alloc(4096 * 4);
    float*          ROPE = (float*)alloc(65536 * 4);
    // VTP (B,H,64,1024) bf16 = 8MB aliased onto XPAD (conv pipeline done first)
    unsigned short* VT   = XPAD;

    hipMemsetAsync(XPAD, 0, 4ll * 1028 * 1024 * 2, stream);
    hipMemsetAsync(H1P, 0, 4ll * 1026 * 512 * 2, stream);

    wtrans_kernel<<<dim3(96, 32, 3), 256, 0, stream>>>(qkv_w, WQ, 1024, 3072);
    wtrans_kernel<<<dim3(32, 32, 3), 256, 0, stream>>>(out_w, WO, 1024, 1024);
    wtrans_kernel<<<dim3(32, 32, 3), 256, 0, stream>>>(gate_w, WG, 1024, 1024);
    wconv_tap_kernel<<<10240, 256, 0, stream>>>(bd_w1, W1S, 1024, 5, 512, 5ll * 512 * 1024);
    wconv_tap_kernel<<<1536, 256, 0, stream>>>(bd_w2, W2S, 512, 3, 256, 3ll * 256 * 512);
    rope_table_kernel<<<128, 256, 0, stream>>>(ROPE);
    embed_kernel<<<512, 1024, 0, stream>>>(patches, embed_w, embed_b, X, XPAD);

    conv_gemm64<5, 1024><<<dim3(32, 8), 512, 0, stream>>>(XPAD, 1028ll * 1024, W1S, 512, bd_b1,
                                                          H1P, 1026ll * 512, 512, 1);
    conv_gemm64<3, 512><<<dim3(32, 4), 512, 0, stream>>>(H1P, 1026ll * 512, W2S, 256, bd_b2,
                                                         H2, 1024ll * 256, 256, 0);
    conv3_kernel<<<1024, 256, 0, stream>>>(H2, bd_w3, bd_b3, LOGI);
    winmax_kernel<<<4, 256, 0, stream>>>(LOGI, (float*)d_out + 4194304);

    for (int l = 0; l < 3; l++) {
        zcrms_kernel<<<4096, 256, 0, stream>>>(X, norm_g + l * 1024, HN);
        qkv_gemm<<<dim3(32, 24), 256, 0, stream>>>(HN, WQ + (long)l * 3072 * 1024,
                                                   qkv_b + l * 3072, QKV, VT, ROPE);
        attn_kernel<<<dim3(64, 8), 256, 0, stream>>>(QKV, VT, LOGI, YATT);
        if (l < 2)
            fused_og<0><<<dim3(32, 8), 512, 0, stream>>>(YATT, WO + (long)l * 1024 * 1024, out_b + l * 1024,
                                                         HN, WG + (long)l * 1024 * 1024, gate_b + l * 1024,
                                                         X, nullptr);
        else
            fused_og<1><<<dim3(32, 8), 512, 0, stream>>>(YATT, WO + (long)l * 1024 * 1024, out_b + l * 1024,
                                                         HN, WG + (long)l * 1024 * 1024, gate_b + l * 1024,
                                                         X, (float*)d_out);
    }
}